// Round 9
// baseline (543.401 us; speedup 1.0000x reference)
//
#include <hip/hip_runtime.h>

#define N_NODES 50000
#define N_EDGES 800000

typedef __attribute__((ext_vector_type(8))) short short8v;
typedef __attribute__((ext_vector_type(4))) float f32x4;

// ---------- shared 32->64->128->32 MLP block (relative smem layout) ----------
constexpr int M_W0T = 0;        // [64][32] transposed
constexpr int M_B0  = 2048;     // 64
constexpr int M_W1T = 2112;     // [128][64] transposed
constexpr int M_B1  = 10304;    // 128
constexpr int M_W2  = 10432;    // [128][32] natural
constexpr int M_B2  = 14528;    // 32
constexpr int M_SZ  = 14560;    // floats

__device__ __forceinline__ void stage_mlp(float* sm,
    const float* __restrict__ W0, const float* __restrict__ b0,
    const float* __restrict__ W1, const float* __restrict__ b1,
    const float* __restrict__ W2, const float* __restrict__ b2,
    int tid, int nthr) {
  for (int t = tid; t < 2048; t += nthr) {
    int j = t >> 5, k = t & 31;
    sm[M_W0T + t] = W0[k * 64 + j];          // W0 is [32][64]
  }
  for (int t = tid; t < 8192; t += nthr) {
    int k2 = t >> 6, j = t & 63;
    sm[M_W1T + t] = W1[j * 128 + k2];        // W1 is [64][128]
  }
  for (int t = tid; t < 4096; t += nthr) sm[M_W2 + t] = W2[t];
  for (int t = tid; t < 64; t += nthr)  sm[M_B0 + t] = b0[t];
  for (int t = tid; t < 128; t += nthr) sm[M_B1 + t] = b1[t];
  for (int t = tid; t < 32; t += nthr)  sm[M_B2 + t] = b2[t];
}

// ------------------------------- CSR build ----------------------------------
__global__ void __launch_bounds__(256) count_kernel(const int* __restrict__ dst,
                                                    int* __restrict__ counts) {
  int e = blockIdx.x * 256 + threadIdx.x;
  if (e < N_EDGES) atomicAdd(&counts[dst[e]], 1);
}

// shfl-based scan: wave-level inclusive scan + 16-partial combine (2 barriers)
__global__ void __launch_bounds__(1024) scan_kernel(int* __restrict__ counts,
                                                    int* __restrict__ offsets) {
  __shared__ int wsum[16];
  const int PER = (N_NODES + 1023) / 1024;  // 49
  int tid = threadIdx.x;
  int base = tid * PER;
  int s = 0;
  for (int i = 0; i < PER; ++i) {
    int idx = base + i;
    if (idx < N_NODES) s += counts[idx];
  }
  int lane = tid & 63, w = tid >> 6;
  int v = s;
#pragma unroll
  for (int off = 1; off < 64; off <<= 1) {
    int t = __shfl_up(v, off);
    if (lane >= off) v += t;
  }
  if (lane == 63) wsum[w] = v;
  __syncthreads();
  int wpre = 0;
#pragma unroll
  for (int i = 0; i < 16; ++i) {
    int t = wsum[i];
    if (i < w) wpre += t;
  }
  int incl = v + wpre;     // inclusive scan of per-thread sums
  int run = incl - s;      // exclusive prefix for this thread's chunk
  for (int i = 0; i < PER; ++i) {
    int idx = base + i;
    if (idx < N_NODES) {
      int c = counts[idx];
      offsets[idx] = run;
      counts[idx] = run;  // cursor for scatter
      run += c;
    }
  }
  if (tid == 1023) offsets[N_NODES] = incl;
}

__global__ void __launch_bounds__(256) scatter_kernel(
    const int* __restrict__ src, const int* __restrict__ dst,
    int* __restrict__ cursor, int2* __restrict__ csr) {
  int e = blockIdx.x * 256 + threadIdx.x;
  if (e >= N_EDGES) return;
  int d = dst[e];
  int slot = atomicAdd(&cursor[d], 1);
  csr[slot] = make_int2(src[e], d);   // one 8B store -> one cacheline
}

// ---------------- weight split-bf16 fragment packing --------------------------
// W1 frags: fi = r*2+f : elem(fi,lane,j) = W1T[k2=r*16+(lane&15)][f*32+(lane>>4)*8+j]
// W2 frags (sigma-permuted k so GEMM2's B comes straight from GEMM1's C layout):
//   fi2 = tt*4+f2 : elem = W2T[cc=tt*16+(lane&15)]
//                          [k2 = f2*32 + (j>>2)*16 + (lane>>4)*4 + (j&3)]
__device__ __forceinline__ ushort bf16hi(float v) {
  return (ushort)(__float_as_uint(v) >> 16);
}

__global__ void __launch_bounds__(256) pack_kernel(
    const float* __restrict__ tW1, const float* __restrict__ tW2,
    ushort* __restrict__ wp) {
  int t = blockIdx.x * 256 + threadIdx.x;
  if (t >= 12288) return;
  float v;
  int hi_off, lo_off;
  if (t < 8192) {
    int fi = t >> 9, lane = (t >> 3) & 63, j = t & 7;
    int r = fi >> 1, f = fi & 1;
    int k2 = r * 16 + (lane & 15);
    int jg = f * 32 + (lane >> 4) * 8 + j;
    v = tW1[jg * 128 + k2];                 // W1 is [64][128]
    hi_off = t; lo_off = 8192 + t;
  } else {
    int t2 = t - 8192;
    int fi = t2 >> 9, lane = (t2 >> 3) & 63, j = t2 & 7;
    int tt = fi >> 2, f2 = fi & 3;
    int cc = tt * 16 + (lane & 15);
    int q = (lane >> 4) & 3;
    int k2 = f2 * 32 + (j >> 2) * 16 + q * 4 + (j & 3);   // sigma(q,f2,j)
    v = tW2[k2 * 32 + cc];                  // W2 is [128][32]
    hi_off = 16384 + t2; lo_off = 20480 + t2;
  }
  ushort h = bf16hi(v);
  float hf = __uint_as_float((unsigned)h << 16);
  ushort l = bf16hi(v - hf);
  wp[hi_off] = h;
  wp[lo_off] = l;
}

// ------------------------------ node kernels ---------------------------------
// x path: out[n][0:64]=a=x@thW+thB ; gp[n][0:64]=g=x@phW+phB-x@thW
constexpr int XK_THT = 0;      // 2048
constexpr int XK_PHT = 2048;   // 2048
constexpr int XK_THB = 4096;   // 64
constexpr int XK_PHB = 4160;   // 64
constexpr int XK_SZ  = 4224;   // 16.9 KB

__global__ void __launch_bounds__(256) node_x_kernel(
    const float* __restrict__ x,
    const float* __restrict__ thW, const float* __restrict__ thB,
    const float* __restrict__ phW, const float* __restrict__ phB,
    float* __restrict__ out, float* __restrict__ gp) {
  __shared__ __align__(16) float sm[XK_SZ];
  const int tid = threadIdx.x;
  for (int t = tid; t < 2048; t += 256) {
    int j = t >> 5, k = t & 31;
    sm[XK_THT + t] = thW[k * 64 + j];
    sm[XK_PHT + t] = phW[k * 64 + j];
  }
  for (int t = tid; t < 64; t += 256) {
    sm[XK_THB + t] = thB[t];
    sm[XK_PHB + t] = phB[t];
  }
  __syncthreads();
  int n = blockIdx.x * 256 + tid;
  if (n >= N_NODES) return;

  float xv[32];
  {
    const float4* p = (const float4*)(x + (long)n * 32);
#pragma unroll
    for (int q = 0; q < 8; ++q) {
      float4 v = p[q];
      xv[q * 4 + 0] = v.x; xv[q * 4 + 1] = v.y;
      xv[q * 4 + 2] = v.z; xv[q * 4 + 3] = v.w;
    }
  }
  float* ao = out + (long)n * 128;
  float* go = gp + (long)n * 128;
  for (int j = 0; j < 64; ++j) {
    float dth = 0.f, dph = 0.f;
#pragma unroll
    for (int k = 0; k < 32; ++k) {
      dth += xv[k] * sm[XK_THT + j * 32 + k];
      dph += xv[k] * sm[XK_PHT + j * 32 + k];
    }
    ao[j] = sm[XK_THB + j] + dth;          // a
    go[j] = sm[XK_PHB + j] + dph - dth;    // g
  }
}

// en path, 2-way k2-split: 512 threads / 256 nodes per block.
// half = tid>>8 handles k2 rows [half*64, half*64+64) of the pen MLP,
// then u[j] and pen[j] for j in [half*32, half*32+32).
constexpr int EK_TW0 = 0;        // 2048
constexpr int EK_MLP = 2048;     // 14560 (pen W0T,B0,W1T,B1,W2,B2)
constexpr int EK_W3T = 16608;    // 2048
constexpr int EK_B3  = 18656;    // 64
constexpr int EK_H2  = 18720;    // 8192 = h2buf[32][256] (transposed, conflict-free)
constexpr int EK_SZ  = 26912;    // 107.6 KB

__global__ void __launch_bounds__(512) node_en_kernel(
    const float* __restrict__ en, const float* __restrict__ tW0,
    const float* __restrict__ pW0, const float* __restrict__ pb0,
    const float* __restrict__ pW1, const float* __restrict__ pb1,
    const float* __restrict__ pW2, const float* __restrict__ pb2,
    const float* __restrict__ pW3, const float* __restrict__ pb3,
    float* __restrict__ gp, float* __restrict__ u) {
  __shared__ __align__(16) float sm[EK_SZ];
  const int tid = threadIdx.x;
  for (int t = tid; t < 2048; t += 512) {
    int j = t >> 5, k = t & 31;
    sm[EK_TW0 + t] = tW0[k * 64 + j];
    sm[EK_W3T + t] = pW3[k * 64 + j];
  }
  for (int t = tid; t < 64; t += 512) sm[EK_B3 + t] = pb3[t];
  stage_mlp(sm + EK_MLP, pW0, pb0, pW1, pb1, pW2, pb2, tid, 512);
  __syncthreads();

  const int half = tid >> 8, nl = tid & 255;
  const int n = blockIdx.x * 256 + nl;
  const bool act = n < N_NODES;

  float ev[32];
#pragma unroll
  for (int k = 0; k < 32; ++k) ev[k] = 0.f;
  if (act) {
    const float4* p = (const float4*)(en + (long)n * 32);
#pragma unroll
    for (int q = 0; q < 8; ++q) {
      float4 v = p[q];
      ev[q * 4 + 0] = v.x; ev[q * 4 + 1] = v.y;
      ev[q * 4 + 2] = v.z; ev[q * 4 + 3] = v.w;
    }
  }

  // full h0 (both halves duplicate this small layer)
  const float* W0T = sm + EK_MLP + M_W0T;
  const float* B0  = sm + EK_MLP + M_B0;
  float h0[64];
#pragma unroll 4
  for (int j = 0; j < 64; ++j) {
    float a0 = B0[j], a1 = 0.f;
    const float* wr = W0T + j * 32;
#pragma unroll
    for (int k = 0; k < 16; ++k) {
      a0 += ev[k] * wr[k];
      a1 += ev[k + 16] * wr[k + 16];
    }
    h0[j] = fmaxf(a0 + a1, 0.f);
  }

  // partial h2 over this half's 64 k2 rows
  const float* W1T = sm + EK_MLP + M_W1T;
  const float* B1  = sm + EK_MLP + M_B1;
  const float* W2s = sm + EK_MLP + M_W2;
  const float* B2  = sm + EK_MLP + M_B2;
  float h2[32];
#pragma unroll
  for (int c = 0; c < 32; ++c) h2[c] = (half == 0) ? B2[c] : 0.f;
  const int k2base = half * 64;
#pragma unroll 2
  for (int i = 0; i < 64; ++i) {
    int k2 = k2base + i;
    const float* wr = W1T + k2 * 64;
    float t0 = B1[k2], t1 = 0.f, t2 = 0.f, t3 = 0.f;
#pragma unroll
    for (int j = 0; j < 16; ++j) {
      t0 += h0[j] * wr[j];
      t1 += h0[j + 16] * wr[j + 16];
      t2 += h0[j + 32] * wr[j + 32];
      t3 += h0[j + 48] * wr[j + 48];
    }
    float t = fmaxf((t0 + t1) + (t2 + t3), 0.f);
    const float* w2r = W2s + k2 * 32;
#pragma unroll
    for (int c = 0; c < 32; ++c) h2[c] += t * w2r[c];
  }

  // combine halves via transposed LDS buffer (lanes hit distinct banks)
  float* H2 = sm + EK_H2;
  if (half == 1) {
#pragma unroll
    for (int c = 0; c < 32; ++c) H2[c * 256 + nl] = h2[c];
  }
  __syncthreads();
  if (half == 0) {
#pragma unroll
    for (int c = 0; c < 32; ++c) h2[c] = fmaxf(h2[c] + H2[c * 256 + nl], 0.f);
#pragma unroll
    for (int c = 0; c < 32; ++c) H2[c * 256 + nl] = h2[c];
  }
  __syncthreads();
  if (half == 1) {
#pragma unroll
    for (int c = 0; c < 32; ++c) h2[c] = H2[c * 256 + nl];
  }
  if (!act) return;

  // u[j] and pen[j] for this half's j-range
  const float* TW0T = sm + EK_TW0;
  float* uo = u + (long)n * 64 + half * 32;
  for (int j4 = 0; j4 < 8; ++j4) {
    float uv[4];
#pragma unroll
    for (int r = 0; r < 4; ++r) {
      int j = half * 32 + j4 * 4 + r;
      const float* wr = TW0T + j * 32;
      float a0 = 0.f, a1 = 0.f;
#pragma unroll
      for (int k = 0; k < 16; ++k) {
        a0 += ev[k] * wr[k];
        a1 += ev[k + 16] * wr[k + 16];
      }
      uv[r] = a0 + a1;
    }
    *(float4*)(uo + j4 * 4) = make_float4(uv[0], uv[1], uv[2], uv[3]);
  }
  const float* W3T = sm + EK_W3T;
  float* go = gp + (long)n * 128 + 64 + half * 32;
  for (int j4 = 0; j4 < 8; ++j4) {
    float ov[4];
#pragma unroll
    for (int r = 0; r < 4; ++r) {
      int j = half * 32 + j4 * 4 + r;
      const float* wr = W3T + j * 32;
      float a0 = sm[EK_B3 + j], a1 = 0.f;
#pragma unroll
      for (int k = 0; k < 16; ++k) {
        a0 += h2[k] * wr[k];
        a1 += h2[k + 16] * wr[k + 16];
      }
      ov[r] = a0 + a1;
    }
    *(float4*)(go + j4 * 4) = make_float4(ov[0], ov[1], ov[2], ov[3]);
  }
}

// ----------- per-edge theta MLP (layers 1,2) via split-bf16 MFMA -------------
// Wave = 16 consecutive CSR slots. C/D layout: col=lane&15, row=(lane>>4)*4+reg.
// GEMM2's B frags come straight from GEMM1's C layout via the sigma k-permutation
// baked into the W2 pack — zero cross-lane shuffles.
__global__ void __launch_bounds__(512) mlp_edge_kernel(
    const float* __restrict__ u,
    const int2* __restrict__ csr,
    const float* __restrict__ b0g, const float* __restrict__ b1g,
    const float* __restrict__ b2g,
    const ushort* __restrict__ wp,
    float* __restrict__ h2sum) {
  __shared__ __align__(16) ushort lds[24576];   // 48 KB
  {
    const uint4* s4 = (const uint4*)wp;
    uint4* d4 = (uint4*)lds;
    for (int i = threadIdx.x; i < 3072; i += 512) d4[i] = s4[i];
  }
  __syncthreads();

  const int lane = threadIdx.x & 63;
  const int q = lane >> 4, c = lane & 15;
  const int wv = threadIdx.x >> 6;
  const int e = (blockIdx.x * 8 + wv) * 16 + c;   // exact fit: 6250*128=800000
  const int2 pr = csr[e];
  const int s = pr.x, d = pr.y;

  const short8v* W1HI = (const short8v*)(lds);
  const short8v* W1LO = (const short8v*)(lds + 8192);
  const short8v* W2HI = (const short8v*)(lds + 16384);
  const short8v* W2LO = (const short8v*)(lds + 20480);

  // ---- build B(h0) frags: frag f covers j = f*32 + q*8 .. +7 ----
  short8v bh0, bl0, bh1, bl1;
  {
    const float* ud = u + (long)d * 64 + q * 8;
    const float* us = u + (long)s * 64 + q * 8;
    const float* bp = b0g + q * 8;
#pragma unroll
    for (int f = 0; f < 2; ++f) {
      float4 d0 = *(const float4*)(ud + f * 32);
      float4 d1 = *(const float4*)(ud + f * 32 + 4);
      float4 s0 = *(const float4*)(us + f * 32);
      float4 s1 = *(const float4*)(us + f * 32 + 4);
      float4 c0 = *(const float4*)(bp + f * 32);
      float4 c1 = *(const float4*)(bp + f * 32 + 4);
      float v[8];
      v[0] = fmaxf(d0.x - s0.x + c0.x, 0.f);
      v[1] = fmaxf(d0.y - s0.y + c0.y, 0.f);
      v[2] = fmaxf(d0.z - s0.z + c0.z, 0.f);
      v[3] = fmaxf(d0.w - s0.w + c0.w, 0.f);
      v[4] = fmaxf(d1.x - s1.x + c1.x, 0.f);
      v[5] = fmaxf(d1.y - s1.y + c1.y, 0.f);
      v[6] = fmaxf(d1.z - s1.z + c1.z, 0.f);
      v[7] = fmaxf(d1.w - s1.w + c1.w, 0.f);
      short8v hh, ll;
#pragma unroll
      for (int j = 0; j < 8; ++j) {
        unsigned uv = __float_as_uint(v[j]);
        hh[j] = (short)(uv >> 16);
        float hf = __uint_as_float(uv & 0xFFFF0000u);
        ll[j] = (short)(__float_as_uint(v[j] - hf) >> 16);
      }
      if (f == 0) { bh0 = hh; bl0 = ll; } else { bh1 = hh; bl1 = ll; }
    }
  }

  // ---- GEMM1: acc[r] = b1 tile + W1T·h0 (hi*hi + lo*hi + hi*lo) ----
  f32x4 acc[8];
#pragma unroll
  for (int r = 0; r < 8; ++r)
    acc[r] = *(const f32x4*)(b1g + r * 16 + q * 4);
#pragma unroll
  for (int r = 0; r < 8; ++r) {
    short8v ah0 = W1HI[(2 * r) * 64 + lane];
    short8v ah1 = W1HI[(2 * r + 1) * 64 + lane];
    short8v al0 = W1LO[(2 * r) * 64 + lane];
    short8v al1 = W1LO[(2 * r + 1) * 64 + lane];
    acc[r] = __builtin_amdgcn_mfma_f32_16x16x32_bf16(ah0, bh0, acc[r], 0, 0, 0);
    acc[r] = __builtin_amdgcn_mfma_f32_16x16x32_bf16(ah1, bh1, acc[r], 0, 0, 0);
    acc[r] = __builtin_amdgcn_mfma_f32_16x16x32_bf16(al0, bh0, acc[r], 0, 0, 0);
    acc[r] = __builtin_amdgcn_mfma_f32_16x16x32_bf16(al1, bh1, acc[r], 0, 0, 0);
    acc[r] = __builtin_amdgcn_mfma_f32_16x16x32_bf16(ah0, bl0, acc[r], 0, 0, 0);
    acc[r] = __builtin_amdgcn_mfma_f32_16x16x32_bf16(ah1, bl1, acc[r], 0, 0, 0);
  }
  float h1v[8][4];
#pragma unroll
  for (int r = 0; r < 8; ++r)
#pragma unroll
    for (int g = 0; g < 4; ++g) h1v[r][g] = fmaxf(acc[r][g], 0.f);

  // ---- B2 frags: lane-local via sigma; slot (f2,j) = h1v[2f2+(j>>2)][j&3] ----
  short8v b2h[4], b2l[4];
#pragma unroll
  for (int f2 = 0; f2 < 4; ++f2) {
    short8v hh, ll;
#pragma unroll
    for (int j = 0; j < 8; ++j) {
      float v = h1v[2 * f2 + (j >> 2)][j & 3];
      unsigned uv = __float_as_uint(v);
      hh[j] = (short)(uv >> 16);
      float hf = __uint_as_float(uv & 0xFFFF0000u);
      ll[j] = (short)(__float_as_uint(v - hf) >> 16);
    }
    b2h[f2] = hh; b2l[f2] = ll;
  }

  // ---- GEMM2: 2 out-tiles × 4 k-frags × 3 split ----
  f32x4 a20 = *(const f32x4*)(b2g + q * 4);
  f32x4 a21 = *(const f32x4*)(b2g + 16 + q * 4);
#pragma unroll
  for (int f2 = 0; f2 < 4; ++f2) {
    short8v ah = W2HI[f2 * 64 + lane];
    short8v al = W2LO[f2 * 64 + lane];
    a20 = __builtin_amdgcn_mfma_f32_16x16x32_bf16(ah, b2h[f2], a20, 0, 0, 0);
    a20 = __builtin_amdgcn_mfma_f32_16x16x32_bf16(al, b2h[f2], a20, 0, 0, 0);
    a20 = __builtin_amdgcn_mfma_f32_16x16x32_bf16(ah, b2l[f2], a20, 0, 0, 0);
    short8v ah1 = W2HI[(4 + f2) * 64 + lane];
    short8v al1 = W2LO[(4 + f2) * 64 + lane];
    a21 = __builtin_amdgcn_mfma_f32_16x16x32_bf16(ah1, b2h[f2], a21, 0, 0, 0);
    a21 = __builtin_amdgcn_mfma_f32_16x16x32_bf16(al1, b2h[f2], a21, 0, 0, 0);
    a21 = __builtin_amdgcn_mfma_f32_16x16x32_bf16(ah1, b2l[f2], a21, 0, 0, 0);
  }
  float h2v[8];
#pragma unroll
  for (int g = 0; g < 4; ++g) {
    h2v[g] = fmaxf(a20[g], 0.f);
    h2v[4 + g] = fmaxf(a21[g], 0.f);
  }

  // ---- 16-wide segmented inclusive sum along edge columns ----
  int dp = __shfl_up(d, 1, 16);
  bool head = (c == 0) || (dp != d);
  int seg = head ? c : 0;
#pragma unroll
  for (int off = 1; off < 16; off <<= 1) {
    int t = __shfl_up(seg, off, 16);
    if (c >= off) seg = max(seg, t);
  }
#pragma unroll
  for (int off = 1; off < 16; off <<= 1) {
    bool take = (c - off) >= seg;
#pragma unroll
    for (int k = 0; k < 8; ++k) {
      float t = __shfl_up(h2v[k], off, 16);
      if (take) h2v[k] += t;
    }
  }
  int dn = __shfl_down(d, 1, 16);
  bool tail = (c == 15) || (dn != d);
  if (tail) {
    float* hs = h2sum + (long)d * 32 + q * 4;   // channel = t*16 + q*4 + g
#pragma unroll
    for (int g = 0; g < 4; ++g) atomicAdd(&hs[g], h2v[g]);
#pragma unroll
    for (int g = 0; g < 4; ++g) atomicAdd(&hs[16 + g], h2v[4 + g]);
  }
}

// ------------------------- final gather / reduce -----------------------------
__global__ void __launch_bounds__(256) gather_kernel(
    const int2* __restrict__ csr, const int* __restrict__ offsets,
    const float* __restrict__ gp, const float* __restrict__ h2sum,
    const float* __restrict__ tW3, const float* __restrict__ tb3,
    float* __restrict__ out) {
  __shared__ float sW3[2048 + 64];
  for (int t = threadIdx.x; t < 2048; t += 256) sW3[t] = tW3[t];
  for (int t = threadIdx.x; t < 64; t += 256) sW3[2048 + t] = tb3[t];
  __syncthreads();
  int n = blockIdx.x * 8 + (threadIdx.x >> 5);
  int l = threadIdx.x & 31;
  int half = l >> 4, j4 = l & 15;
  int off = half * 64 + j4 * 4;
  int o0 = offsets[n], o1 = offsets[n + 1];
  int deg = o1 - o0;

  const float NEG = -3.402823466e38f;
  float4 mx = make_float4(NEG, NEG, NEG, NEG);
  float4 sm4 = make_float4(0.f, 0.f, 0.f, 0.f);
  for (int t = o0; t < o1; ++t) {
    int s = csr[t].x;
    float4 v = *(const float4*)(gp + (long)s * 128 + off);
    mx.x = fmaxf(mx.x, v.x); mx.y = fmaxf(mx.y, v.y);
    mx.z = fmaxf(mx.z, v.z); mx.w = fmaxf(mx.w, v.w);
    sm4.x += v.x; sm4.y += v.y; sm4.z += v.z; sm4.w += v.w;
  }

  float4 r;
  if (half == 0) {
    float4 a = *(const float4*)(out + (long)n * 128 + off);
    bool has = deg > 0;
    r.x = has ? a.x + mx.x : 0.f;
    r.y = has ? a.y + mx.y : 0.f;
    r.z = has ? a.z + mx.z : 0.f;
    r.w = has ? a.w + mx.w : 0.f;
  } else {
    int jj = j4 * 4;
    float w30 = 0.f, w31 = 0.f, w32 = 0.f, w33 = 0.f;
    const float* h2r = h2sum + (long)n * 32;
#pragma unroll
    for (int k = 0; k < 32; ++k) {
      float h = h2r[k];
      const float* wrow = &sW3[k * 64 + jj];
      w30 += h * wrow[0]; w31 += h * wrow[1];
      w32 += h * wrow[2]; w33 += h * wrow[3];
    }
    float dg = (float)deg;
    float inv = 1.f / fmaxf(dg, 1.f);
    r.x = (sm4.x + w30 + dg * sW3[2048 + jj + 0]) * inv;
    r.y = (sm4.y + w31 + dg * sW3[2048 + jj + 1]) * inv;
    r.z = (sm4.z + w32 + dg * sW3[2048 + jj + 2]) * inv;
    r.w = (sm4.w + w33 + dg * sW3[2048 + jj + 3]) * inv;
  }
  *(float4*)(out + (long)n * 128 + off) = r;
}

// ---------------------------------- launch -----------------------------------
extern "C" void kernel_launch(void* const* d_in, const int* in_sizes, int n_in,
                              void* d_out, int out_size, void* d_ws,
                              size_t ws_size, hipStream_t stream) {
  const float* x   = (const float*)d_in[0];
  const float* en  = (const float*)d_in[1];
  const int* src   = (const int*)d_in[2];
  const int* dst   = (const int*)d_in[3];
  const float* thW = (const float*)d_in[4];
  const float* thB = (const float*)d_in[5];
  const float* phW = (const float*)d_in[6];
  const float* phB = (const float*)d_in[7];
  const float* tW0 = (const float*)d_in[8];
  const float* tb0 = (const float*)d_in[9];
  const float* tW1 = (const float*)d_in[10];
  const float* tb1 = (const float*)d_in[11];
  const float* tW2 = (const float*)d_in[12];
  const float* tb2 = (const float*)d_in[13];
  const float* tW3 = (const float*)d_in[14];
  const float* tb3 = (const float*)d_in[15];
  const float* pW0 = (const float*)d_in[16];
  const float* pb0 = (const float*)d_in[17];
  const float* pW1 = (const float*)d_in[18];
  const float* pb1 = (const float*)d_in[19];
  const float* pW2 = (const float*)d_in[20];
  const float* pb2 = (const float*)d_in[21];
  const float* pW3 = (const float*)d_in[22];
  const float* pb3 = (const float*)d_in[23];

  float* out = (float*)d_out;
  float* ws  = (float*)d_ws;
  // ws layout (floats): gp[N*128], u[N*64], h2sum[N*32], wpack[12288], ints
  float* gp     = ws;                           // 6,400,000
  float* u      = ws + (long)N_NODES * 128;     // 3,200,000
  float* h2sum  = ws + (long)N_NODES * 192;     // 1,600,000
  float* wpf    = ws + (long)N_NODES * 224;     // 12,288 (24576 ushorts)
  ushort* wp    = (ushort*)wpf;
  int* iw       = (int*)(wpf + 12288);
  int2* csr     = (int2*)iw;                    // E pairs (src,dst)
  int* counts   = iw + 2 * N_EDGES;             // N (becomes cursor)
  int* offsets  = counts + N_NODES;             // N+1
  // total ws ≈ 51.7 MB

  hipMemsetAsync(counts, 0, N_NODES * sizeof(int), stream);
  hipMemsetAsync(h2sum, 0, (size_t)N_NODES * 32 * sizeof(float), stream);
  pack_kernel<<<48, 256, 0, stream>>>(tW1, tW2, wp);
  count_kernel<<<(N_EDGES + 255) / 256, 256, 0, stream>>>(dst, counts);
  scan_kernel<<<1, 1024, 0, stream>>>(counts, offsets);
  scatter_kernel<<<(N_EDGES + 255) / 256, 256, 0, stream>>>(
      src, dst, counts, csr);
  node_x_kernel<<<(N_NODES + 255) / 256, 256, 0, stream>>>(
      x, thW, thB, phW, phB, out, gp);
  node_en_kernel<<<(N_NODES + 255) / 256, 512, 0, stream>>>(
      en, tW0, pW0, pb0, pW1, pb1, pW2, pb2, pW3, pb3, gp, u);
  mlp_edge_kernel<<<N_EDGES / 128, 512, 0, stream>>>(
      u, csr, tb0, tb1, tb2, wp, h2sum);
  gather_kernel<<<N_NODES / 8, 256, 0, stream>>>(
      csr, offsets, gp, h2sum, tW3, tb3, out);
}

// Round 10
// 397.395 us; speedup vs baseline: 1.3674x; 1.3674x over previous
//
#include <hip/hip_runtime.h>

#define N_NODES 50000
#define N_EDGES 800000

typedef __attribute__((ext_vector_type(8))) short short8v;
typedef __attribute__((ext_vector_type(4))) float f32x4;

// ---------- shared 32->64->128->32 MLP block (relative smem layout) ----------
constexpr int M_W0T = 0;        // [64][32] transposed
constexpr int M_B0  = 2048;     // 64
constexpr int M_W1T = 2112;     // [128][64] transposed
constexpr int M_B1  = 10304;    // 128
constexpr int M_W2  = 10432;    // [128][32] natural
constexpr int M_B2  = 14528;    // 32
constexpr int M_SZ  = 14560;    // floats

__device__ __forceinline__ void stage_mlp(float* sm,
    const float* __restrict__ W0, const float* __restrict__ b0,
    const float* __restrict__ W1, const float* __restrict__ b1,
    const float* __restrict__ W2, const float* __restrict__ b2,
    int tid, int nthr) {
  for (int t = tid; t < 2048; t += nthr) {
    int j = t >> 5, k = t & 31;
    sm[M_W0T + t] = W0[k * 64 + j];          // W0 is [32][64]
  }
  for (int t = tid; t < 8192; t += nthr) {
    int k2 = t >> 6, j = t & 63;
    sm[M_W1T + t] = W1[j * 128 + k2];        // W1 is [64][128]
  }
  for (int t = tid; t < 4096; t += nthr) sm[M_W2 + t] = W2[t];
  for (int t = tid; t < 64; t += nthr)  sm[M_B0 + t] = b0[t];
  for (int t = tid; t < 128; t += nthr) sm[M_B1 + t] = b1[t];
  for (int t = tid; t < 32; t += nthr)  sm[M_B2 + t] = b2[t];
}

__device__ __forceinline__ void mlp_core(const float* sm, const float den[32],
                                         float h2[32]) {
  float h0[64];
#pragma unroll
  for (int j = 0; j < 64; ++j) {
    float a = sm[M_B0 + j];
#pragma unroll
    for (int k = 0; k < 32; ++k) a += den[k] * sm[M_W0T + j * 32 + k];
    h0[j] = fmaxf(a, 0.f);
  }
#pragma unroll
  for (int j = 0; j < 32; ++j) h2[j] = sm[M_B2 + j];
  for (int k2 = 0; k2 < 128; ++k2) {
    float t = sm[M_B1 + k2];
#pragma unroll
    for (int j = 0; j < 64; ++j) t += h0[j] * sm[M_W1T + k2 * 64 + j];
    t = fmaxf(t, 0.f);
#pragma unroll
    for (int j = 0; j < 32; ++j) h2[j] += t * sm[M_W2 + k2 * 32 + j];
  }
#pragma unroll
  for (int j = 0; j < 32; ++j) h2[j] = fmaxf(h2[j], 0.f);
}

// ------------------------------- CSR build ----------------------------------
__global__ void __launch_bounds__(256) count_kernel(const int* __restrict__ dst,
                                                    int* __restrict__ counts) {
  int e = blockIdx.x * 256 + threadIdx.x;
  if (e < N_EDGES) atomicAdd(&counts[dst[e]], 1);
}

// Hierarchical scan: scan1 = coalesced per-block (1024-elem) exclusive prefix
// into offsets + block sums; scan2 = add block prefix, write cursor copy.
#define SCAN_NB ((N_NODES + 1023) / 1024)   // 49

__global__ void __launch_bounds__(1024) scan1_kernel(
    const int* __restrict__ counts, int* __restrict__ offsets,
    int* __restrict__ bsum) {
  __shared__ int wsum[16];
  int t = threadIdx.x, b = blockIdx.x;
  int idx = b * 1024 + t;
  int c = (idx < N_NODES) ? counts[idx] : 0;
  int lane = t & 63, w = t >> 6;
  int v = c;
#pragma unroll
  for (int off = 1; off < 64; off <<= 1) {
    int tt = __shfl_up(v, off);
    if (lane >= off) v += tt;
  }
  if (lane == 63) wsum[w] = v;
  __syncthreads();
  int wpre = 0;
#pragma unroll
  for (int i = 0; i < 16; ++i) {
    int tt = wsum[i];
    if (i < w) wpre += tt;
  }
  int incl = v + wpre;
  if (idx < N_NODES) offsets[idx] = incl - c;   // exclusive-within-block
  if (t == 1023) bsum[b] = incl;                // block total
}

__global__ void __launch_bounds__(1024) scan2_kernel(
    const int* __restrict__ bsum, int* __restrict__ offsets,
    int* __restrict__ counts) {
  __shared__ int sb[SCAN_NB];
  int t = threadIdx.x, b = blockIdx.x;
  if (t < SCAN_NB) sb[t] = bsum[t];
  __syncthreads();
  int bpre = 0;
#pragma unroll
  for (int i = 0; i < SCAN_NB; ++i) {
    int tt = sb[i];
    if (i < b) bpre += tt;
  }
  int idx = b * 1024 + t;
  if (idx < N_NODES) {
    int v = offsets[idx] + bpre;
    offsets[idx] = v;
    counts[idx] = v;          // cursor for scatter
  }
  if (b == 0 && t == 0) offsets[N_NODES] = N_EDGES;
}

__global__ void __launch_bounds__(256) scatter_kernel(
    const int* __restrict__ src, const int* __restrict__ dst,
    int* __restrict__ cursor, int2* __restrict__ csr) {
  int e = blockIdx.x * 256 + threadIdx.x;
  if (e >= N_EDGES) return;
  int d = dst[e];
  int slot = atomicAdd(&cursor[d], 1);
  csr[slot] = make_int2(src[e], d);   // one 8B store -> one cacheline
}

// ---------------- weight split-bf16 fragment packing --------------------------
// W1 frags: fi = r*2+f : elem(fi,lane,j) = W1T[k2=r*16+(lane&15)][f*32+(lane>>4)*8+j]
// W2 frags (sigma-permuted k so GEMM2's B comes straight from GEMM1's C layout):
//   fi2 = tt*4+f2 : elem = W2T[cc=tt*16+(lane&15)]
//                          [k2 = f2*32 + (j>>2)*16 + (lane>>4)*4 + (j&3)]
__device__ __forceinline__ ushort bf16hi(float v) {
  return (ushort)(__float_as_uint(v) >> 16);
}

__global__ void __launch_bounds__(256) pack_kernel(
    const float* __restrict__ tW1, const float* __restrict__ tW2,
    ushort* __restrict__ wp) {
  int t = blockIdx.x * 256 + threadIdx.x;
  if (t >= 12288) return;
  float v;
  int hi_off, lo_off;
  if (t < 8192) {
    int fi = t >> 9, lane = (t >> 3) & 63, j = t & 7;
    int r = fi >> 1, f = fi & 1;
    int k2 = r * 16 + (lane & 15);
    int jg = f * 32 + (lane >> 4) * 8 + j;
    v = tW1[jg * 128 + k2];                 // W1 is [64][128]
    hi_off = t; lo_off = 8192 + t;
  } else {
    int t2 = t - 8192;
    int fi = t2 >> 9, lane = (t2 >> 3) & 63, j = t2 & 7;
    int tt = fi >> 2, f2 = fi & 3;
    int cc = tt * 16 + (lane & 15);
    int q = (lane >> 4) & 3;
    int k2 = f2 * 32 + (j >> 2) * 16 + q * 4 + (j & 3);   // sigma(q,f2,j)
    v = tW2[k2 * 32 + cc];                  // W2 is [128][32]
    hi_off = 16384 + t2; lo_off = 20480 + t2;
  }
  ushort h = bf16hi(v);
  float hf = __uint_as_float((unsigned)h << 16);
  ushort l = bf16hi(v - hf);
  wp[hi_off] = h;
  wp[lo_off] = l;
}

// ------------------------------ node kernels ---------------------------------
// x path: out[n][0:64]=a=x@thW+thB ; gp[n][0:64]=g=x@phW+phB-x@thW
constexpr int XK_THT = 0;      // 2048
constexpr int XK_PHT = 2048;   // 2048
constexpr int XK_THB = 4096;   // 64
constexpr int XK_PHB = 4160;   // 64
constexpr int XK_SZ  = 4224;   // 16.9 KB

__global__ void __launch_bounds__(256) node_x_kernel(
    const float* __restrict__ x,
    const float* __restrict__ thW, const float* __restrict__ thB,
    const float* __restrict__ phW, const float* __restrict__ phB,
    float* __restrict__ out, float* __restrict__ gp) {
  __shared__ __align__(16) float sm[XK_SZ];
  const int tid = threadIdx.x;
  for (int t = tid; t < 2048; t += 256) {
    int j = t >> 5, k = t & 31;
    sm[XK_THT + t] = thW[k * 64 + j];
    sm[XK_PHT + t] = phW[k * 64 + j];
  }
  for (int t = tid; t < 64; t += 256) {
    sm[XK_THB + t] = thB[t];
    sm[XK_PHB + t] = phB[t];
  }
  __syncthreads();
  int n = blockIdx.x * 256 + tid;
  if (n >= N_NODES) return;

  float xv[32];
  {
    const float4* p = (const float4*)(x + (long)n * 32);
#pragma unroll
    for (int q = 0; q < 8; ++q) {
      float4 v = p[q];
      xv[q * 4 + 0] = v.x; xv[q * 4 + 1] = v.y;
      xv[q * 4 + 2] = v.z; xv[q * 4 + 3] = v.w;
    }
  }
  float* ao = out + (long)n * 128;
  float* go = gp + (long)n * 128;
  for (int j = 0; j < 64; ++j) {
    float dth = 0.f, dph = 0.f;
#pragma unroll
    for (int k = 0; k < 32; ++k) {
      dth += xv[k] * sm[XK_THT + j * 32 + k];
      dph += xv[k] * sm[XK_PHT + j * 32 + k];
    }
    ao[j] = sm[XK_THB + j] + dth;          // a
    go[j] = sm[XK_PHB + j] + dph - dth;    // g
  }
}

// en path (round-8 proven version): u[n]=en@tW0 ; gp[n][64:128]=pen MLP(en[n])
constexpr int EK_TW0 = 0;        // 2048
constexpr int EK_MLP = 2048;     // 14560
constexpr int EK_W3T = 16608;    // 2048
constexpr int EK_B3  = 18656;    // 64
constexpr int EK_SZ  = 18720;    // 74.9 KB

__global__ void __launch_bounds__(256) node_en_kernel(
    const float* __restrict__ en, const float* __restrict__ tW0,
    const float* __restrict__ pW0, const float* __restrict__ pb0,
    const float* __restrict__ pW1, const float* __restrict__ pb1,
    const float* __restrict__ pW2, const float* __restrict__ pb2,
    const float* __restrict__ pW3, const float* __restrict__ pb3,
    float* __restrict__ gp, float* __restrict__ u) {
  __shared__ __align__(16) float sm[EK_SZ];
  const int tid = threadIdx.x;
  for (int t = tid; t < 2048; t += 256) {
    int j = t >> 5, k = t & 31;
    sm[EK_TW0 + t] = tW0[k * 64 + j];
    sm[EK_W3T + t] = pW3[k * 64 + j];
  }
  for (int t = tid; t < 64; t += 256) sm[EK_B3 + t] = pb3[t];
  stage_mlp(sm + EK_MLP, pW0, pb0, pW1, pb1, pW2, pb2, tid, 256);
  __syncthreads();
  int n = blockIdx.x * 256 + tid;
  if (n >= N_NODES) return;

  float ev[32];
  {
    const float4* p = (const float4*)(en + (long)n * 32);
#pragma unroll
    for (int q = 0; q < 8; ++q) {
      float4 v = p[q];
      ev[q * 4 + 0] = v.x; ev[q * 4 + 1] = v.y;
      ev[q * 4 + 2] = v.z; ev[q * 4 + 3] = v.w;
    }
  }
  float* uo = u + (long)n * 64;
  for (int j = 0; j < 64; ++j) {
    float a = 0.f;
#pragma unroll
    for (int k = 0; k < 32; ++k) a += ev[k] * sm[EK_TW0 + j * 32 + k];
    uo[j] = a;
  }
  float h2p[32];
  mlp_core(sm + EK_MLP, ev, h2p);
  float* go = gp + (long)n * 128 + 64;
  for (int j = 0; j < 64; ++j) {
    float o = sm[EK_B3 + j];
#pragma unroll
    for (int k = 0; k < 32; ++k) o += h2p[k] * sm[EK_W3T + j * 32 + k];
    go[j] = o;                             // pen
  }
}

// ----------- per-edge theta MLP (layers 1,2) via split-bf16 MFMA -------------
// Wave = 16 consecutive CSR slots. C/D layout: col=lane&15, row=(lane>>4)*4+reg.
// GEMM2's B frags come straight from GEMM1's C layout via the sigma k-permutation
// baked into the W2 pack — zero cross-lane shuffles.
__global__ void __launch_bounds__(512) mlp_edge_kernel(
    const float* __restrict__ u,
    const int2* __restrict__ csr,
    const float* __restrict__ b0g, const float* __restrict__ b1g,
    const float* __restrict__ b2g,
    const ushort* __restrict__ wp,
    float* __restrict__ h2sum) {
  __shared__ __align__(16) ushort lds[24576];   // 48 KB
  {
    const uint4* s4 = (const uint4*)wp;
    uint4* d4 = (uint4*)lds;
    for (int i = threadIdx.x; i < 3072; i += 512) d4[i] = s4[i];
  }
  __syncthreads();

  const int lane = threadIdx.x & 63;
  const int q = lane >> 4, c = lane & 15;
  const int wv = threadIdx.x >> 6;
  const int e = (blockIdx.x * 8 + wv) * 16 + c;   // exact fit: 6250*128=800000
  const int2 pr = csr[e];
  const int s = pr.x, d = pr.y;

  const short8v* W1HI = (const short8v*)(lds);
  const short8v* W1LO = (const short8v*)(lds + 8192);
  const short8v* W2HI = (const short8v*)(lds + 16384);
  const short8v* W2LO = (const short8v*)(lds + 20480);

  // ---- build B(h0) frags: frag f covers j = f*32 + q*8 .. +7 ----
  short8v bh0, bl0, bh1, bl1;
  {
    const float* ud = u + (long)d * 64 + q * 8;
    const float* us = u + (long)s * 64 + q * 8;
    const float* bp = b0g + q * 8;
#pragma unroll
    for (int f = 0; f < 2; ++f) {
      float4 d0 = *(const float4*)(ud + f * 32);
      float4 d1 = *(const float4*)(ud + f * 32 + 4);
      float4 s0 = *(const float4*)(us + f * 32);
      float4 s1 = *(const float4*)(us + f * 32 + 4);
      float4 c0 = *(const float4*)(bp + f * 32);
      float4 c1 = *(const float4*)(bp + f * 32 + 4);
      float v[8];
      v[0] = fmaxf(d0.x - s0.x + c0.x, 0.f);
      v[1] = fmaxf(d0.y - s0.y + c0.y, 0.f);
      v[2] = fmaxf(d0.z - s0.z + c0.z, 0.f);
      v[3] = fmaxf(d0.w - s0.w + c0.w, 0.f);
      v[4] = fmaxf(d1.x - s1.x + c1.x, 0.f);
      v[5] = fmaxf(d1.y - s1.y + c1.y, 0.f);
      v[6] = fmaxf(d1.z - s1.z + c1.z, 0.f);
      v[7] = fmaxf(d1.w - s1.w + c1.w, 0.f);
      short8v hh, ll;
#pragma unroll
      for (int j = 0; j < 8; ++j) {
        unsigned uv = __float_as_uint(v[j]);
        hh[j] = (short)(uv >> 16);
        float hf = __uint_as_float(uv & 0xFFFF0000u);
        ll[j] = (short)(__float_as_uint(v[j] - hf) >> 16);
      }
      if (f == 0) { bh0 = hh; bl0 = ll; } else { bh1 = hh; bl1 = ll; }
    }
  }

  // ---- GEMM1: acc[r] = b1 tile + W1T·h0 (hi*hi + lo*hi + hi*lo) ----
  f32x4 acc[8];
#pragma unroll
  for (int r = 0; r < 8; ++r)
    acc[r] = *(const f32x4*)(b1g + r * 16 + q * 4);
#pragma unroll
  for (int r = 0; r < 8; ++r) {
    short8v ah0 = W1HI[(2 * r) * 64 + lane];
    short8v ah1 = W1HI[(2 * r + 1) * 64 + lane];
    short8v al0 = W1LO[(2 * r) * 64 + lane];
    short8v al1 = W1LO[(2 * r + 1) * 64 + lane];
    acc[r] = __builtin_amdgcn_mfma_f32_16x16x32_bf16(ah0, bh0, acc[r], 0, 0, 0);
    acc[r] = __builtin_amdgcn_mfma_f32_16x16x32_bf16(ah1, bh1, acc[r], 0, 0, 0);
    acc[r] = __builtin_amdgcn_mfma_f32_16x16x32_bf16(al0, bh0, acc[r], 0, 0, 0);
    acc[r] = __builtin_amdgcn_mfma_f32_16x16x32_bf16(al1, bh1, acc[r], 0, 0, 0);
    acc[r] = __builtin_amdgcn_mfma_f32_16x16x32_bf16(ah0, bl0, acc[r], 0, 0, 0);
    acc[r] = __builtin_amdgcn_mfma_f32_16x16x32_bf16(ah1, bl1, acc[r], 0, 0, 0);
  }
  float h1v[8][4];
#pragma unroll
  for (int r = 0; r < 8; ++r)
#pragma unroll
    for (int g = 0; g < 4; ++g) h1v[r][g] = fmaxf(acc[r][g], 0.f);

  // ---- B2 frags: lane-local via sigma; slot (f2,j) = h1v[2f2+(j>>2)][j&3] ----
  short8v b2h[4], b2l[4];
#pragma unroll
  for (int f2 = 0; f2 < 4; ++f2) {
    short8v hh, ll;
#pragma unroll
    for (int j = 0; j < 8; ++j) {
      float v = h1v[2 * f2 + (j >> 2)][j & 3];
      unsigned uv = __float_as_uint(v);
      hh[j] = (short)(uv >> 16);
      float hf = __uint_as_float(uv & 0xFFFF0000u);
      ll[j] = (short)(__float_as_uint(v - hf) >> 16);
    }
    b2h[f2] = hh; b2l[f2] = ll;
  }

  // ---- GEMM2: 2 out-tiles × 4 k-frags × 3 split ----
  f32x4 a20 = *(const f32x4*)(b2g + q * 4);
  f32x4 a21 = *(const f32x4*)(b2g + 16 + q * 4);
#pragma unroll
  for (int f2 = 0; f2 < 4; ++f2) {
    short8v ah = W2HI[f2 * 64 + lane];
    short8v al = W2LO[f2 * 64 + lane];
    a20 = __builtin_amdgcn_mfma_f32_16x16x32_bf16(ah, b2h[f2], a20, 0, 0, 0);
    a20 = __builtin_amdgcn_mfma_f32_16x16x32_bf16(al, b2h[f2], a20, 0, 0, 0);
    a20 = __builtin_amdgcn_mfma_f32_16x16x32_bf16(ah, b2l[f2], a20, 0, 0, 0);
    short8v ah1 = W2HI[(4 + f2) * 64 + lane];
    short8v al1 = W2LO[(4 + f2) * 64 + lane];
    a21 = __builtin_amdgcn_mfma_f32_16x16x32_bf16(ah1, b2h[f2], a21, 0, 0, 0);
    a21 = __builtin_amdgcn_mfma_f32_16x16x32_bf16(al1, b2h[f2], a21, 0, 0, 0);
    a21 = __builtin_amdgcn_mfma_f32_16x16x32_bf16(ah1, b2l[f2], a21, 0, 0, 0);
  }
  float h2v[8];
#pragma unroll
  for (int g = 0; g < 4; ++g) {
    h2v[g] = fmaxf(a20[g], 0.f);
    h2v[4 + g] = fmaxf(a21[g], 0.f);
  }

  // ---- 16-wide segmented inclusive sum along edge columns ----
  int dp = __shfl_up(d, 1, 16);
  bool head = (c == 0) || (dp != d);
  int seg = head ? c : 0;
#pragma unroll
  for (int off = 1; off < 16; off <<= 1) {
    int t = __shfl_up(seg, off, 16);
    if (c >= off) seg = max(seg, t);
  }
#pragma unroll
  for (int off = 1; off < 16; off <<= 1) {
    bool take = (c - off) >= seg;
#pragma unroll
    for (int k = 0; k < 8; ++k) {
      float t = __shfl_up(h2v[k], off, 16);
      if (take) h2v[k] += t;
    }
  }
  int dn = __shfl_down(d, 1, 16);
  bool tail = (c == 15) || (dn != d);
  if (tail) {
    float* hs = h2sum + (long)d * 32 + q * 4;   // channel = t*16 + q*4 + g
#pragma unroll
    for (int g = 0; g < 4; ++g) atomicAdd(&hs[g], h2v[g]);
#pragma unroll
    for (int g = 0; g < 4; ++g) atomicAdd(&hs[16 + g], h2v[4 + g]);
  }
}

// ------------------------- final gather / reduce -----------------------------
__global__ void __launch_bounds__(256) gather_kernel(
    const int2* __restrict__ csr, const int* __restrict__ offsets,
    const float* __restrict__ gp, const float* __restrict__ h2sum,
    const float* __restrict__ tW3, const float* __restrict__ tb3,
    float* __restrict__ out) {
  __shared__ float sW3[2048 + 64];
  for (int t = threadIdx.x; t < 2048; t += 256) sW3[t] = tW3[t];
  for (int t = threadIdx.x; t < 64; t += 256) sW3[2048 + t] = tb3[t];
  __syncthreads();
  int n = blockIdx.x * 8 + (threadIdx.x >> 5);
  int l = threadIdx.x & 31;
  int half = l >> 4, j4 = l & 15;
  int off = half * 64 + j4 * 4;
  int o0 = offsets[n], o1 = offsets[n + 1];
  int deg = o1 - o0;

  const float NEG = -3.402823466e38f;
  float4 mx = make_float4(NEG, NEG, NEG, NEG);
  float4 sm4 = make_float4(0.f, 0.f, 0.f, 0.f);
  for (int t = o0; t < o1; ++t) {
    int s = csr[t].x;
    float4 v = *(const float4*)(gp + (long)s * 128 + off);
    mx.x = fmaxf(mx.x, v.x); mx.y = fmaxf(mx.y, v.y);
    mx.z = fmaxf(mx.z, v.z); mx.w = fmaxf(mx.w, v.w);
    sm4.x += v.x; sm4.y += v.y; sm4.z += v.z; sm4.w += v.w;
  }

  float4 r;
  if (half == 0) {
    float4 a = *(const float4*)(out + (long)n * 128 + off);
    bool has = deg > 0;
    r.x = has ? a.x + mx.x : 0.f;
    r.y = has ? a.y + mx.y : 0.f;
    r.z = has ? a.z + mx.z : 0.f;
    r.w = has ? a.w + mx.w : 0.f;
  } else {
    int jj = j4 * 4;
    float w30 = 0.f, w31 = 0.f, w32 = 0.f, w33 = 0.f;
    const float* h2r = h2sum + (long)n * 32;
#pragma unroll
    for (int k = 0; k < 32; ++k) {
      float h = h2r[k];
      const float* wrow = &sW3[k * 64 + jj];
      w30 += h * wrow[0]; w31 += h * wrow[1];
      w32 += h * wrow[2]; w33 += h * wrow[3];
    }
    float dg = (float)deg;
    float inv = 1.f / fmaxf(dg, 1.f);
    r.x = (sm4.x + w30 + dg * sW3[2048 + jj + 0]) * inv;
    r.y = (sm4.y + w31 + dg * sW3[2048 + jj + 1]) * inv;
    r.z = (sm4.z + w32 + dg * sW3[2048 + jj + 2]) * inv;
    r.w = (sm4.w + w33 + dg * sW3[2048 + jj + 3]) * inv;
  }
  *(float4*)(out + (long)n * 128 + off) = r;
}

// ---------------------------------- launch -----------------------------------
extern "C" void kernel_launch(void* const* d_in, const int* in_sizes, int n_in,
                              void* d_out, int out_size, void* d_ws,
                              size_t ws_size, hipStream_t stream) {
  const float* x   = (const float*)d_in[0];
  const float* en  = (const float*)d_in[1];
  const int* src   = (const int*)d_in[2];
  const int* dst   = (const int*)d_in[3];
  const float* thW = (const float*)d_in[4];
  const float* thB = (const float*)d_in[5];
  const float* phW = (const float*)d_in[6];
  const float* phB = (const float*)d_in[7];
  const float* tW0 = (const float*)d_in[8];
  const float* tb0 = (const float*)d_in[9];
  const float* tW1 = (const float*)d_in[10];
  const float* tb1 = (const float*)d_in[11];
  const float* tW2 = (const float*)d_in[12];
  const float* tb2 = (const float*)d_in[13];
  const float* tW3 = (const float*)d_in[14];
  const float* tb3 = (const float*)d_in[15];
  const float* pW0 = (const float*)d_in[16];
  const float* pb0 = (const float*)d_in[17];
  const float* pW1 = (const float*)d_in[18];
  const float* pb1 = (const float*)d_in[19];
  const float* pW2 = (const float*)d_in[20];
  const float* pb2 = (const float*)d_in[21];
  const float* pW3 = (const float*)d_in[22];
  const float* pb3 = (const float*)d_in[23];

  float* out = (float*)d_out;
  float* ws  = (float*)d_ws;
  // ws layout (floats): gp[N*128], u[N*64], h2sum[N*32], wpack[12288], ints
  float* gp     = ws;                           // 6,400,000
  float* u      = ws + (long)N_NODES * 128;     // 3,200,000
  float* h2sum  = ws + (long)N_NODES * 192;     // 1,600,000
  float* wpf    = ws + (long)N_NODES * 224;     // 12,288 (24576 ushorts)
  ushort* wp    = (ushort*)wpf;
  int* iw       = (int*)(wpf + 12288);
  int2* csr     = (int2*)iw;                    // E pairs (src,dst)
  int* counts   = iw + 2 * N_EDGES;             // N (becomes cursor)
  int* offsets  = counts + N_NODES;             // N+1
  int* bsum     = offsets + N_NODES + 1;        // SCAN_NB
  // total ws ≈ 51.7 MB

  hipMemsetAsync(counts, 0, N_NODES * sizeof(int), stream);
  hipMemsetAsync(h2sum, 0, (size_t)N_NODES * 32 * sizeof(float), stream);
  pack_kernel<<<48, 256, 0, stream>>>(tW1, tW2, wp);
  count_kernel<<<(N_EDGES + 255) / 256, 256, 0, stream>>>(dst, counts);
  scan1_kernel<<<SCAN_NB, 1024, 0, stream>>>(counts, offsets, bsum);
  scan2_kernel<<<SCAN_NB, 1024, 0, stream>>>(bsum, offsets, counts);
  scatter_kernel<<<(N_EDGES + 255) / 256, 256, 0, stream>>>(
      src, dst, counts, csr);
  node_x_kernel<<<(N_NODES + 255) / 256, 256, 0, stream>>>(
      x, thW, thB, phW, phB, out, gp);
  node_en_kernel<<<(N_NODES + 255) / 256, 256, 0, stream>>>(
      en, tW0, pW0, pb0, pW1, pb1, pW2, pb2, pW3, pb3, gp, u);
  mlp_edge_kernel<<<N_EDGES / 128, 512, 0, stream>>>(
      u, csr, tb0, tb1, tb2, wp, h2sum);
  gather_kernel<<<N_NODES / 8, 256, 0, stream>>>(
      csr, offsets, gp, h2sum, tW3, tb3, out);
}

// Round 11
// 355.239 us; speedup vs baseline: 1.5297x; 1.1187x over previous
//
#include <hip/hip_runtime.h>

#define N_NODES 50000
#define N_EDGES 800000

typedef __attribute__((ext_vector_type(8))) short short8v;
typedef __attribute__((ext_vector_type(4))) float f32x4;

// ---------- shared 32->64->128->32 MLP block (relative smem layout) ----------
constexpr int M_W0T = 0;        // [64][32] transposed
constexpr int M_B0  = 2048;     // 64
constexpr int M_W1T = 2112;     // [128][64] transposed
constexpr int M_B1  = 10304;    // 128
constexpr int M_W2  = 10432;    // [128][32] natural
constexpr int M_B2  = 14528;    // 32
constexpr int M_SZ  = 14560;    // floats

__device__ __forceinline__ void stage_mlp(float* sm,
    const float* __restrict__ W0, const float* __restrict__ b0,
    const float* __restrict__ W1, const float* __restrict__ b1,
    const float* __restrict__ W2, const float* __restrict__ b2,
    int tid, int nthr) {
  for (int t = tid; t < 2048; t += nthr) {
    int j = t >> 5, k = t & 31;
    sm[M_W0T + t] = W0[k * 64 + j];          // W0 is [32][64]
  }
  for (int t = tid; t < 8192; t += nthr) {
    int k2 = t >> 6, j = t & 63;
    sm[M_W1T + t] = W1[j * 128 + k2];        // W1 is [64][128]
  }
  for (int t = tid; t < 4096; t += nthr) sm[M_W2 + t] = W2[t];
  for (int t = tid; t < 64; t += nthr)  sm[M_B0 + t] = b0[t];
  for (int t = tid; t < 128; t += nthr) sm[M_B1 + t] = b1[t];
  for (int t = tid; t < 32; t += nthr)  sm[M_B2 + t] = b2[t];
}

__device__ __forceinline__ void mlp_core(const float* sm, const float den[32],
                                         float h2[32]) {
  float h0[64];
#pragma unroll
  for (int j = 0; j < 64; ++j) {
    float a = sm[M_B0 + j];
#pragma unroll
    for (int k = 0; k < 32; ++k) a += den[k] * sm[M_W0T + j * 32 + k];
    h0[j] = fmaxf(a, 0.f);
  }
#pragma unroll
  for (int j = 0; j < 32; ++j) h2[j] = sm[M_B2 + j];
  for (int k2 = 0; k2 < 128; ++k2) {
    float t = sm[M_B1 + k2];
#pragma unroll
    for (int j = 0; j < 64; ++j) t += h0[j] * sm[M_W1T + k2 * 64 + j];
    t = fmaxf(t, 0.f);
#pragma unroll
    for (int j = 0; j < 32; ++j) h2[j] += t * sm[M_W2 + k2 * 32 + j];
  }
#pragma unroll
  for (int j = 0; j < 32; ++j) h2[j] = fmaxf(h2[j], 0.f);
}

__device__ __forceinline__ ushort bf16hi(float v) {
  return (ushort)(__float_as_uint(v) >> 16);
}

// ---------------- node_en LDS layout ----------------
constexpr int EK_TW0 = 0;        // 2048
constexpr int EK_MLP = 2048;     // 14560
constexpr int EK_W3T = 16608;    // 2048
constexpr int EK_B3  = 18656;    // 64
constexpr int EK_SZ  = 18720;    // 74.9 KB

// ======================= combo_a: node_en | count | pack ======================
// blocks [0,196)       : node_en (u[n]=en@tW0 ; gp[n][64:128]=pen MLP(en[n]))
// blocks [196,3321)    : count   (histogram of dst)
// blocks [3321,3369)   : pack    (split-bf16 weight fragments)
#define CA_EN 196
#define CA_CNT 3125
#define CA_PACK 48

__global__ void __launch_bounds__(256) combo_a_kernel(
    const float* __restrict__ en, const float* __restrict__ tW0,
    const float* __restrict__ pW0, const float* __restrict__ pb0,
    const float* __restrict__ pW1, const float* __restrict__ pb1,
    const float* __restrict__ pW2, const float* __restrict__ pb2,
    const float* __restrict__ pW3, const float* __restrict__ pb3,
    float* __restrict__ gp, float* __restrict__ u,
    const int* __restrict__ dst, int* __restrict__ counts,
    const float* __restrict__ tW1, const float* __restrict__ tW2,
    ushort* __restrict__ wp) {
  const int b = blockIdx.x;
  const int tid = threadIdx.x;
  if (b < CA_EN) {
    // ----------------- node_en path (round-8 proven body) -----------------
    __shared__ __align__(16) float sm[EK_SZ];
    for (int t = tid; t < 2048; t += 256) {
      int j = t >> 5, k = t & 31;
      sm[EK_TW0 + t] = tW0[k * 64 + j];
      sm[EK_W3T + t] = pW3[k * 64 + j];
    }
    for (int t = tid; t < 64; t += 256) sm[EK_B3 + t] = pb3[t];
    stage_mlp(sm + EK_MLP, pW0, pb0, pW1, pb1, pW2, pb2, tid, 256);
    __syncthreads();
    int n = b * 256 + tid;
    if (n >= N_NODES) return;

    float ev[32];
    {
      const float4* p = (const float4*)(en + (long)n * 32);
#pragma unroll
      for (int q = 0; q < 8; ++q) {
        float4 v = p[q];
        ev[q * 4 + 0] = v.x; ev[q * 4 + 1] = v.y;
        ev[q * 4 + 2] = v.z; ev[q * 4 + 3] = v.w;
      }
    }
    float* uo = u + (long)n * 64;
    for (int j = 0; j < 64; ++j) {
      float a = 0.f;
#pragma unroll
      for (int k = 0; k < 32; ++k) a += ev[k] * sm[EK_TW0 + j * 32 + k];
      uo[j] = a;
    }
    float h2p[32];
    mlp_core(sm + EK_MLP, ev, h2p);
    float* go = gp + (long)n * 128 + 64;
    for (int j = 0; j < 64; ++j) {
      float o = sm[EK_B3 + j];
#pragma unroll
      for (int k = 0; k < 32; ++k) o += h2p[k] * sm[EK_W3T + j * 32 + k];
      go[j] = o;                             // pen
    }
  } else if (b < CA_EN + CA_CNT) {
    // ----------------------------- count path -----------------------------
    int e = (b - CA_EN) * 256 + tid;
    if (e < N_EDGES) atomicAdd(&counts[dst[e]], 1);
  } else {
    // ----------------------------- pack path ------------------------------
    int t = (b - CA_EN - CA_CNT) * 256 + tid;
    if (t >= 12288) return;
    float v;
    int hi_off, lo_off;
    if (t < 8192) {
      int fi = t >> 9, lane = (t >> 3) & 63, j = t & 7;
      int r = fi >> 1, f = fi & 1;
      int k2 = r * 16 + (lane & 15);
      int jg = f * 32 + (lane >> 4) * 8 + j;
      v = tW1[jg * 128 + k2];                 // W1 is [64][128]
      hi_off = t; lo_off = 8192 + t;
    } else {
      int t2 = t - 8192;
      int fi = t2 >> 9, lane = (t2 >> 3) & 63, j = t2 & 7;
      int tt = fi >> 2, f2 = fi & 3;
      int cc = tt * 16 + (lane & 15);
      int q = (lane >> 4) & 3;
      int k2 = f2 * 32 + (j >> 2) * 16 + q * 4 + (j & 3);   // sigma(q,f2,j)
      v = tW2[k2 * 32 + cc];                  // W2 is [128][32]
      hi_off = 16384 + t2; lo_off = 20480 + t2;
    }
    ushort h = bf16hi(v);
    float hf = __uint_as_float((unsigned)h << 16);
    ushort l = bf16hi(v - hf);
    wp[hi_off] = h;
    wp[lo_off] = l;
  }
}

// ------------------------------- scan --------------------------------------
#define SCAN_NB ((N_NODES + 1023) / 1024)   // 49

__global__ void __launch_bounds__(1024) scan1_kernel(
    const int* __restrict__ counts, int* __restrict__ offsets,
    int* __restrict__ bsum) {
  __shared__ int wsum[16];
  int t = threadIdx.x, b = blockIdx.x;
  int idx = b * 1024 + t;
  int c = (idx < N_NODES) ? counts[idx] : 0;
  int lane = t & 63, w = t >> 6;
  int v = c;
#pragma unroll
  for (int off = 1; off < 64; off <<= 1) {
    int tt = __shfl_up(v, off);
    if (lane >= off) v += tt;
  }
  if (lane == 63) wsum[w] = v;
  __syncthreads();
  int wpre = 0;
#pragma unroll
  for (int i = 0; i < 16; ++i) {
    int tt = wsum[i];
    if (i < w) wpre += tt;
  }
  int incl = v + wpre;
  if (idx < N_NODES) offsets[idx] = incl - c;   // exclusive-within-block
  if (t == 1023) bsum[b] = incl;                // block total
}

__global__ void __launch_bounds__(1024) scan2_kernel(
    const int* __restrict__ bsum, int* __restrict__ offsets,
    int* __restrict__ counts) {
  __shared__ int sb[SCAN_NB];
  int t = threadIdx.x, b = blockIdx.x;
  if (t < SCAN_NB) sb[t] = bsum[t];
  __syncthreads();
  int bpre = 0;
#pragma unroll
  for (int i = 0; i < SCAN_NB; ++i) {
    int tt = sb[i];
    if (i < b) bpre += tt;
  }
  int idx = b * 1024 + t;
  if (idx < N_NODES) {
    int v = offsets[idx] + bpre;
    offsets[idx] = v;
    counts[idx] = v;          // cursor for scatter
  }
  if (b == 0 && t == 0) offsets[N_NODES] = N_EDGES;
}

// ======================= combo_b: node_x | scatter ===========================
// blocks [0,196)    : node_x (out[n][0:64]=a ; gp[n][0:64]=g)
// blocks [196,3321) : scatter (CSR build)
#define CB_X 196
#define CB_SC 3125

constexpr int XK_THT = 0;      // 2048
constexpr int XK_PHT = 2048;   // 2048
constexpr int XK_THB = 4096;   // 64
constexpr int XK_PHB = 4160;   // 64
constexpr int XK_SZ  = 4224;   // 16.9 KB

__global__ void __launch_bounds__(256) combo_b_kernel(
    const float* __restrict__ x,
    const float* __restrict__ thW, const float* __restrict__ thB,
    const float* __restrict__ phW, const float* __restrict__ phB,
    float* __restrict__ out, float* __restrict__ gp,
    const int* __restrict__ src, const int* __restrict__ dst,
    int* __restrict__ cursor, int2* __restrict__ csr) {
  const int b = blockIdx.x;
  const int tid = threadIdx.x;
  if (b < CB_X) {
    // ------------------------------ node_x path ----------------------------
    __shared__ __align__(16) float sm[XK_SZ];
    for (int t = tid; t < 2048; t += 256) {
      int j = t >> 5, k = t & 31;
      sm[XK_THT + t] = thW[k * 64 + j];
      sm[XK_PHT + t] = phW[k * 64 + j];
    }
    for (int t = tid; t < 64; t += 256) {
      sm[XK_THB + t] = thB[t];
      sm[XK_PHB + t] = phB[t];
    }
    __syncthreads();
    int n = b * 256 + tid;
    if (n >= N_NODES) return;

    float xv[32];
    {
      const float4* p = (const float4*)(x + (long)n * 32);
#pragma unroll
      for (int q = 0; q < 8; ++q) {
        float4 v = p[q];
        xv[q * 4 + 0] = v.x; xv[q * 4 + 1] = v.y;
        xv[q * 4 + 2] = v.z; xv[q * 4 + 3] = v.w;
      }
    }
    float* ao = out + (long)n * 128;
    float* go = gp + (long)n * 128;
    for (int j = 0; j < 64; ++j) {
      float dth = 0.f, dph = 0.f;
#pragma unroll
      for (int k = 0; k < 32; ++k) {
        dth += xv[k] * sm[XK_THT + j * 32 + k];
        dph += xv[k] * sm[XK_PHT + j * 32 + k];
      }
      ao[j] = sm[XK_THB + j] + dth;          // a
      go[j] = sm[XK_PHB + j] + dph - dth;    // g
    }
  } else {
    // ------------------------------ scatter path ---------------------------
    int e = (b - CB_X) * 256 + tid;
    if (e >= N_EDGES) return;
    int d = dst[e];
    int slot = atomicAdd(&cursor[d], 1);
    csr[slot] = make_int2(src[e], d);   // one 8B store -> one cacheline
  }
}

// ----------- per-edge theta MLP (layers 1,2) via split-bf16 MFMA -------------
// Wave = 16 consecutive CSR slots. C/D layout: col=lane&15, row=(lane>>4)*4+reg.
// sigma k-permutation baked into W2 pack -> zero cross-lane shuffles.
// XCD-bijective blockIdx swizzle: each XCD covers a contiguous sorted-d range
// so its u[d] slice (~1.6 MB) is L2-resident.
__global__ void __launch_bounds__(512) mlp_edge_kernel(
    const float* __restrict__ u,
    const int2* __restrict__ csr,
    const float* __restrict__ b0g, const float* __restrict__ b1g,
    const float* __restrict__ b2g,
    const ushort* __restrict__ wp,
    float* __restrict__ h2sum) {
  __shared__ __align__(16) ushort lds[24576];   // 48 KB
  {
    const uint4* s4 = (const uint4*)wp;
    uint4* d4 = (uint4*)lds;
    for (int i = threadIdx.x; i < 3072; i += 512) d4[i] = s4[i];
  }
  __syncthreads();

  // bijective XCD swizzle (nwg=6250, q=781, r=2; m204 form)
  const int orig = blockIdx.x;
  const int xcd = orig & 7, loc = orig >> 3;
  const int blk = (xcd < 2) ? xcd * 782 + loc
                            : 2 * 782 + (xcd - 2) * 781 + loc;

  const int lane = threadIdx.x & 63;
  const int q = lane >> 4, c = lane & 15;
  const int wv = threadIdx.x >> 6;
  const int e = (blk * 8 + wv) * 16 + c;   // exact fit: 6250*128=800000
  const int2 pr = csr[e];
  const int s = pr.x, d = pr.y;

  const short8v* W1HI = (const short8v*)(lds);
  const short8v* W1LO = (const short8v*)(lds + 8192);
  const short8v* W2HI = (const short8v*)(lds + 16384);
  const short8v* W2LO = (const short8v*)(lds + 20480);

  // ---- build B(h0) frags: frag f covers j = f*32 + q*8 .. +7 ----
  short8v bh0, bl0, bh1, bl1;
  {
    const float* ud = u + (long)d * 64 + q * 8;
    const float* us = u + (long)s * 64 + q * 8;
    const float* bp = b0g + q * 8;
#pragma unroll
    for (int f = 0; f < 2; ++f) {
      float4 d0 = *(const float4*)(ud + f * 32);
      float4 d1 = *(const float4*)(ud + f * 32 + 4);
      float4 s0 = *(const float4*)(us + f * 32);
      float4 s1 = *(const float4*)(us + f * 32 + 4);
      float4 c0 = *(const float4*)(bp + f * 32);
      float4 c1 = *(const float4*)(bp + f * 32 + 4);
      float v[8];
      v[0] = fmaxf(d0.x - s0.x + c0.x, 0.f);
      v[1] = fmaxf(d0.y - s0.y + c0.y, 0.f);
      v[2] = fmaxf(d0.z - s0.z + c0.z, 0.f);
      v[3] = fmaxf(d0.w - s0.w + c0.w, 0.f);
      v[4] = fmaxf(d1.x - s1.x + c1.x, 0.f);
      v[5] = fmaxf(d1.y - s1.y + c1.y, 0.f);
      v[6] = fmaxf(d1.z - s1.z + c1.z, 0.f);
      v[7] = fmaxf(d1.w - s1.w + c1.w, 0.f);
      short8v hh, ll;
#pragma unroll
      for (int j = 0; j < 8; ++j) {
        unsigned uv = __float_as_uint(v[j]);
        hh[j] = (short)(uv >> 16);
        float hf = __uint_as_float(uv & 0xFFFF0000u);
        ll[j] = (short)(__float_as_uint(v[j] - hf) >> 16);
      }
      if (f == 0) { bh0 = hh; bl0 = ll; } else { bh1 = hh; bl1 = ll; }
    }
  }

  // ---- GEMM1: acc[r] = b1 tile + W1T·h0 (hi*hi + lo*hi + hi*lo) ----
  f32x4 acc[8];
#pragma unroll
  for (int r = 0; r < 8; ++r)
    acc[r] = *(const f32x4*)(b1g + r * 16 + q * 4);
#pragma unroll
  for (int r = 0; r < 8; ++r) {
    short8v ah0 = W1HI[(2 * r) * 64 + lane];
    short8v ah1 = W1HI[(2 * r + 1) * 64 + lane];
    short8v al0 = W1LO[(2 * r) * 64 + lane];
    short8v al1 = W1LO[(2 * r + 1) * 64 + lane];
    acc[r] = __builtin_amdgcn_mfma_f32_16x16x32_bf16(ah0, bh0, acc[r], 0, 0, 0);
    acc[r] = __builtin_amdgcn_mfma_f32_16x16x32_bf16(ah1, bh1, acc[r], 0, 0, 0);
    acc[r] = __builtin_amdgcn_mfma_f32_16x16x32_bf16(al0, bh0, acc[r], 0, 0, 0);
    acc[r] = __builtin_amdgcn_mfma_f32_16x16x32_bf16(al1, bh1, acc[r], 0, 0, 0);
    acc[r] = __builtin_amdgcn_mfma_f32_16x16x32_bf16(ah0, bl0, acc[r], 0, 0, 0);
    acc[r] = __builtin_amdgcn_mfma_f32_16x16x32_bf16(ah1, bl1, acc[r], 0, 0, 0);
  }
  float h1v[8][4];
#pragma unroll
  for (int r = 0; r < 8; ++r)
#pragma unroll
    for (int g = 0; g < 4; ++g) h1v[r][g] = fmaxf(acc[r][g], 0.f);

  // ---- B2 frags: lane-local via sigma; slot (f2,j) = h1v[2f2+(j>>2)][j&3] ----
  short8v b2h[4], b2l[4];
#pragma unroll
  for (int f2 = 0; f2 < 4; ++f2) {
    short8v hh, ll;
#pragma unroll
    for (int j = 0; j < 8; ++j) {
      float v = h1v[2 * f2 + (j >> 2)][j & 3];
      unsigned uv = __float_as_uint(v);
      hh[j] = (short)(uv >> 16);
      float hf = __uint_as_float(uv & 0xFFFF0000u);
      ll[j] = (short)(__float_as_uint(v - hf) >> 16);
    }
    b2h[f2] = hh; b2l[f2] = ll;
  }

  // ---- GEMM2: 2 out-tiles × 4 k-frags × 3 split ----
  f32x4 a20 = *(const f32x4*)(b2g + q * 4);
  f32x4 a21 = *(const f32x4*)(b2g + 16 + q * 4);
#pragma unroll
  for (int f2 = 0; f2 < 4; ++f2) {
    short8v ah = W2HI[f2 * 64 + lane];
    short8v al = W2LO[f2 * 64 + lane];
    a20 = __builtin_amdgcn_mfma_f32_16x16x32_bf16(ah, b2h[f2], a20, 0, 0, 0);
    a20 = __builtin_amdgcn_mfma_f32_16x16x32_bf16(al, b2h[f2], a20, 0, 0, 0);
    a20 = __builtin_amdgcn_mfma_f32_16x16x32_bf16(ah, b2l[f2], a20, 0, 0, 0);
    short8v ah1 = W2HI[(4 + f2) * 64 + lane];
    short8v al1 = W2LO[(4 + f2) * 64 + lane];
    a21 = __builtin_amdgcn_mfma_f32_16x16x32_bf16(ah1, b2h[f2], a21, 0, 0, 0);
    a21 = __builtin_amdgcn_mfma_f32_16x16x32_bf16(al1, b2h[f2], a21, 0, 0, 0);
    a21 = __builtin_amdgcn_mfma_f32_16x16x32_bf16(ah1, b2l[f2], a21, 0, 0, 0);
  }
  float h2v[8];
#pragma unroll
  for (int g = 0; g < 4; ++g) {
    h2v[g] = fmaxf(a20[g], 0.f);
    h2v[4 + g] = fmaxf(a21[g], 0.f);
  }

  // ---- 16-wide segmented inclusive sum along edge columns ----
  int dp = __shfl_up(d, 1, 16);
  bool head = (c == 0) || (dp != d);
  int seg = head ? c : 0;
#pragma unroll
  for (int off = 1; off < 16; off <<= 1) {
    int t = __shfl_up(seg, off, 16);
    if (c >= off) seg = max(seg, t);
  }
#pragma unroll
  for (int off = 1; off < 16; off <<= 1) {
    bool take = (c - off) >= seg;
#pragma unroll
    for (int k = 0; k < 8; ++k) {
      float t = __shfl_up(h2v[k], off, 16);
      if (take) h2v[k] += t;
    }
  }
  int dn = __shfl_down(d, 1, 16);
  bool tail = (c == 15) || (dn != d);
  if (tail) {
    float* hs = h2sum + (long)d * 32 + q * 4;   // channel = t*16 + q*4 + g
#pragma unroll
    for (int g = 0; g < 4; ++g) atomicAdd(&hs[g], h2v[g]);
#pragma unroll
    for (int g = 0; g < 4; ++g) atomicAdd(&hs[16 + g], h2v[4 + g]);
  }
}

// ------------------------- final gather / reduce -----------------------------
__global__ void __launch_bounds__(256) gather_kernel(
    const int2* __restrict__ csr, const int* __restrict__ offsets,
    const float* __restrict__ gp, const float* __restrict__ h2sum,
    const float* __restrict__ tW3, const float* __restrict__ tb3,
    float* __restrict__ out) {
  __shared__ float sW3[2048 + 64];
  for (int t = threadIdx.x; t < 2048; t += 256) sW3[t] = tW3[t];
  for (int t = threadIdx.x; t < 64; t += 256) sW3[2048 + t] = tb3[t];
  __syncthreads();
  int n = blockIdx.x * 8 + (threadIdx.x >> 5);
  int l = threadIdx.x & 31;
  int half = l >> 4, j4 = l & 15;
  int off = half * 64 + j4 * 4;
  int o0 = offsets[n], o1 = offsets[n + 1];
  int deg = o1 - o0;

  const float NEG = -3.402823466e38f;
  float4 mx = make_float4(NEG, NEG, NEG, NEG);
  float4 sm4 = make_float4(0.f, 0.f, 0.f, 0.f);
  for (int t = o0; t < o1; ++t) {
    int s = csr[t].x;
    float4 v = *(const float4*)(gp + (long)s * 128 + off);
    mx.x = fmaxf(mx.x, v.x); mx.y = fmaxf(mx.y, v.y);
    mx.z = fmaxf(mx.z, v.z); mx.w = fmaxf(mx.w, v.w);
    sm4.x += v.x; sm4.y += v.y; sm4.z += v.z; sm4.w += v.w;
  }

  float4 r;
  if (half == 0) {
    float4 a = *(const float4*)(out + (long)n * 128 + off);
    bool has = deg > 0;
    r.x = has ? a.x + mx.x : 0.f;
    r.y = has ? a.y + mx.y : 0.f;
    r.z = has ? a.z + mx.z : 0.f;
    r.w = has ? a.w + mx.w : 0.f;
  } else {
    int jj = j4 * 4;
    float w30 = 0.f, w31 = 0.f, w32 = 0.f, w33 = 0.f;
    const float* h2r = h2sum + (long)n * 32;
#pragma unroll
    for (int k = 0; k < 32; ++k) {
      float h = h2r[k];
      const float* wrow = &sW3[k * 64 + jj];
      w30 += h * wrow[0]; w31 += h * wrow[1];
      w32 += h * wrow[2]; w33 += h * wrow[3];
    }
    float dg = (float)deg;
    float inv = 1.f / fmaxf(dg, 1.f);
    r.x = (sm4.x + w30 + dg * sW3[2048 + jj + 0]) * inv;
    r.y = (sm4.y + w31 + dg * sW3[2048 + jj + 1]) * inv;
    r.z = (sm4.z + w32 + dg * sW3[2048 + jj + 2]) * inv;
    r.w = (sm4.w + w33 + dg * sW3[2048 + jj + 3]) * inv;
  }
  *(float4*)(out + (long)n * 128 + off) = r;
}

// ---------------------------------- launch -----------------------------------
extern "C" void kernel_launch(void* const* d_in, const int* in_sizes, int n_in,
                              void* d_out, int out_size, void* d_ws,
                              size_t ws_size, hipStream_t stream) {
  const float* x   = (const float*)d_in[0];
  const float* en  = (const float*)d_in[1];
  const int* src   = (const int*)d_in[2];
  const int* dst   = (const int*)d_in[3];
  const float* thW = (const float*)d_in[4];
  const float* thB = (const float*)d_in[5];
  const float* phW = (const float*)d_in[6];
  const float* phB = (const float*)d_in[7];
  const float* tW0 = (const float*)d_in[8];
  const float* tb0 = (const float*)d_in[9];
  const float* tW1 = (const float*)d_in[10];
  const float* tb1 = (const float*)d_in[11];
  const float* tW2 = (const float*)d_in[12];
  const float* tb2 = (const float*)d_in[13];
  const float* tW3 = (const float*)d_in[14];
  const float* tb3 = (const float*)d_in[15];
  const float* pW0 = (const float*)d_in[16];
  const float* pb0 = (const float*)d_in[17];
  const float* pW1 = (const float*)d_in[18];
  const float* pb1 = (const float*)d_in[19];
  const float* pW2 = (const float*)d_in[20];
  const float* pb2 = (const float*)d_in[21];
  const float* pW3 = (const float*)d_in[22];
  const float* pb3 = (const float*)d_in[23];

  float* out = (float*)d_out;
  float* ws  = (float*)d_ws;
  // ws layout (floats): gp[N*128], u[N*64], h2sum[N*32], wpack[12288], ints
  float* gp     = ws;                           // 6,400,000
  float* u      = ws + (long)N_NODES * 128;     // 3,200,000
  float* h2sum  = ws + (long)N_NODES * 192;     // 1,600,000
  float* wpf    = ws + (long)N_NODES * 224;     // 12,288 (24576 ushorts)
  ushort* wp    = (ushort*)wpf;
  int* iw       = (int*)(wpf + 12288);
  int2* csr     = (int2*)iw;                    // E pairs (src,dst)
  int* counts   = iw + 2 * N_EDGES;             // N (becomes cursor)
  int* offsets  = counts + N_NODES;             // N+1
  int* bsum     = offsets + N_NODES + 1;        // SCAN_NB
  // total ws ≈ 51.7 MB

  hipMemsetAsync(counts, 0, N_NODES * sizeof(int), stream);
  hipMemsetAsync(h2sum, 0, (size_t)N_NODES * 32 * sizeof(float), stream);
  combo_a_kernel<<<CA_EN + CA_CNT + CA_PACK, 256, 0, stream>>>(
      en, tW0, pW0, pb0, pW1, pb1, pW2, pb2, pW3, pb3, gp, u,
      dst, counts, tW1, tW2, wp);
  scan1_kernel<<<SCAN_NB, 1024, 0, stream>>>(counts, offsets, bsum);
  scan2_kernel<<<SCAN_NB, 1024, 0, stream>>>(bsum, offsets, counts);
  combo_b_kernel<<<CB_X + CB_SC, 256, 0, stream>>>(
      x, thW, thB, phW, phB, out, gp, src, dst, counts, csr);
  mlp_edge_kernel<<<N_EDGES / 128, 512, 0, stream>>>(
      u, csr, tb0, tb1, tb2, wp, h2sum);
  gather_kernel<<<N_NODES / 8, 256, 0, stream>>>(
      csr, offsets, gp, h2sum, tW3, tb3, out);
}

// Round 12
// 316.676 us; speedup vs baseline: 1.7160x; 1.1218x over previous
//
#include <hip/hip_runtime.h>

#define N_NODES 50000
#define N_EDGES 800000

typedef __attribute__((ext_vector_type(8))) short short8v;
typedef __attribute__((ext_vector_type(4))) float f32x4;

__device__ __forceinline__ ushort bf16hi(float v) {
  return (ushort)(__float_as_uint(v) >> 16);
}

__device__ __forceinline__ void split8(const float v[8], short8v& hh, short8v& ll) {
#pragma unroll
  for (int j = 0; j < 8; ++j) {
    unsigned uv = __float_as_uint(v[j]);
    hh[j] = (short)(uv >> 16);
    float hf = __uint_as_float(uv & 0xFFFF0000u);
    ll[j] = (short)(__float_as_uint(v[j] - hf) >> 16);
  }
}

// ==================== combo1: node_x | count | pack ==========================
// blocks [0,196)       : node_x  (out[n][0:64]=a ; gp[n][0:64]=g)
// blocks [196,3321)    : count   (histogram of dst)
// blocks [3321,3441)   : pack    (split-bf16 weight fragments, 30720 slots)
#define C1_X 196
#define C1_CNT 3125
#define C1_PACK 120

constexpr int XK_THT = 0;      // 2048
constexpr int XK_PHT = 2048;   // 2048
constexpr int XK_THB = 4096;   // 64
constexpr int XK_PHB = 4160;   // 64
constexpr int XK_SZ  = 4224;   // 16.9 KB

// wp layout (ushort offsets):
//  edge: W1 hi [0,8192) lo [8192,16384) | W2sig(tW2) hi [16384,20480) lo [20480,24576)
//  node: tW0 hi 24576 lo 26624 | pW0 hi 28672 lo 30720 | pW1s1 hi 32768 lo 40960
//        pW2sig hi 49152 lo 53248 | pW3s3 hi 57344 lo 59392 | end 61440
__global__ void __launch_bounds__(256) combo1_kernel(
    const float* __restrict__ x,
    const float* __restrict__ thW, const float* __restrict__ thB,
    const float* __restrict__ phW, const float* __restrict__ phB,
    float* __restrict__ out, float* __restrict__ gp,
    const int* __restrict__ dst, int* __restrict__ counts,
    const float* __restrict__ tW1, const float* __restrict__ tW2,
    const float* __restrict__ tW0, const float* __restrict__ pW0,
    const float* __restrict__ pW1, const float* __restrict__ pW2,
    const float* __restrict__ pW3, ushort* __restrict__ wp) {
  const int b = blockIdx.x;
  const int tid = threadIdx.x;
  if (b < C1_X) {
    // ------------------------------ node_x ---------------------------------
    __shared__ __align__(16) float sm[XK_SZ];
    for (int t = tid; t < 2048; t += 256) {
      int j = t >> 5, k = t & 31;
      sm[XK_THT + t] = thW[k * 64 + j];
      sm[XK_PHT + t] = phW[k * 64 + j];
    }
    for (int t = tid; t < 64; t += 256) {
      sm[XK_THB + t] = thB[t];
      sm[XK_PHB + t] = phB[t];
    }
    __syncthreads();
    int n = b * 256 + tid;
    if (n >= N_NODES) return;

    float xv[32];
    {
      const float4* p = (const float4*)(x + (long)n * 32);
#pragma unroll
      for (int q = 0; q < 8; ++q) {
        float4 v = p[q];
        xv[q * 4 + 0] = v.x; xv[q * 4 + 1] = v.y;
        xv[q * 4 + 2] = v.z; xv[q * 4 + 3] = v.w;
      }
    }
    float* ao = out + (long)n * 128;
    float* go = gp + (long)n * 128;
    for (int j = 0; j < 64; ++j) {
      float dth = 0.f, dph = 0.f;
#pragma unroll
      for (int k = 0; k < 32; ++k) {
        dth += xv[k] * sm[XK_THT + j * 32 + k];
        dph += xv[k] * sm[XK_PHT + j * 32 + k];
      }
      ao[j] = sm[XK_THB + j] + dth;          // a
      go[j] = sm[XK_PHB + j] + dph - dth;    // g
    }
  } else if (b < C1_X + C1_CNT) {
    // ------------------------------- count ---------------------------------
    int e = (b - C1_X) * 256 + tid;
    if (e < N_EDGES) atomicAdd(&counts[dst[e]], 1);
  } else {
    // -------------------------------- pack ---------------------------------
    int t = (b - C1_X - C1_CNT) * 256 + tid;
    if (t >= 30720) return;
    float v;
    int hi_off, lo_off;
    if (t < 8192) {
      // edge W1 natural frags
      int fi = t >> 9, lane = (t >> 3) & 63, j = t & 7;
      int r = fi >> 1, f = fi & 1;
      int k2 = r * 16 + (lane & 15);
      int jg = f * 32 + (lane >> 4) * 8 + j;
      v = tW1[jg * 128 + k2];
      hi_off = t; lo_off = 8192 + t;
    } else if (t < 12288) {
      // edge W2 sigma frags
      int t2 = t - 8192;
      int fi = t2 >> 9, lane = (t2 >> 3) & 63, j = t2 & 7;
      int tt = fi >> 2, f2 = fi & 3;
      int cc = tt * 16 + (lane & 15);
      int qq = (lane >> 4) & 3;
      int k2 = f2 * 32 + (j >> 2) * 16 + qq * 4 + (j & 3);
      v = tW2[k2 * 32 + cc];
      hi_off = 16384 + t2; lo_off = 20480 + t2;
    } else if (t < 16384) {
      // node W0-type frags (tW0 then pW0), natural K
      int t3 = t - 12288;
      const float* M = (t3 < 2048) ? tW0 : pW0;
      int tt3 = t3 & 2047;
      int fi = tt3 >> 9, lane = (tt3 >> 3) & 63, j = tt3 & 7;
      int row = fi * 16 + (lane & 15);
      int k = (lane >> 4) * 8 + j;
      v = M[k * 64 + row];
      hi_off = ((t3 < 2048) ? 24576 : 28672) + tt3;
      lo_off = hi_off + 2048;
    } else if (t < 24576) {
      // node pW1 sigma1 frags: k = 32f + 16(j>>2) + 4q + (j&3)
      int t5 = t - 16384;
      int fi = t5 >> 9, lane = (t5 >> 3) & 63, j = t5 & 7;
      int r = fi >> 1, f = fi & 1;
      int row = r * 16 + (lane & 15);
      int sig = 32 * f + 16 * (j >> 2) + 4 * ((lane >> 4) & 3) + (j & 3);
      v = pW1[sig * 128 + row];
      hi_off = 32768 + t5; lo_off = 40960 + t5;
    } else if (t < 28672) {
      // node pW2 sigma frags (same sigma as edge W2)
      int t6 = t - 24576;
      int fi = t6 >> 9, lane = (t6 >> 3) & 63, j = t6 & 7;
      int tt = fi >> 2, f2 = fi & 3;
      int cc = tt * 16 + (lane & 15);
      int qq = (lane >> 4) & 3;
      int k2 = f2 * 32 + (j >> 2) * 16 + qq * 4 + (j & 3);
      v = pW2[k2 * 32 + cc];
      hi_off = 49152 + t6; lo_off = 53248 + t6;
    } else {
      // node pW3 sigma3 frags: k = 16(j>>2) + 4q + (j&3)
      int t7 = t - 28672;
      int fi = t7 >> 9, lane = (t7 >> 3) & 63, j = t7 & 7;
      int row = fi * 16 + (lane & 15);
      int sig = 16 * (j >> 2) + 4 * ((lane >> 4) & 3) + (j & 3);
      v = pW3[sig * 64 + row];
      hi_off = 57344 + t7; lo_off = 59392 + t7;
    }
    ushort h = bf16hi(v);
    float hf = __uint_as_float((unsigned)h << 16);
    ushort l = bf16hi(v - hf);
    wp[hi_off] = h;
    wp[lo_off] = l;
  }
}

// ------------------------------- scan --------------------------------------
#define SCAN_NB ((N_NODES + 1023) / 1024)   // 49

__global__ void __launch_bounds__(1024) scan1_kernel(
    const int* __restrict__ counts, int* __restrict__ offsets,
    int* __restrict__ bsum) {
  __shared__ int wsum[16];
  int t = threadIdx.x, b = blockIdx.x;
  int idx = b * 1024 + t;
  int c = (idx < N_NODES) ? counts[idx] : 0;
  int lane = t & 63, w = t >> 6;
  int v = c;
#pragma unroll
  for (int off = 1; off < 64; off <<= 1) {
    int tt = __shfl_up(v, off);
    if (lane >= off) v += tt;
  }
  if (lane == 63) wsum[w] = v;
  __syncthreads();
  int wpre = 0;
#pragma unroll
  for (int i = 0; i < 16; ++i) {
    int tt = wsum[i];
    if (i < w) wpre += tt;
  }
  int incl = v + wpre;
  if (idx < N_NODES) offsets[idx] = incl - c;   // exclusive-within-block
  if (t == 1023) bsum[b] = incl;                // block total
}

__global__ void __launch_bounds__(1024) scan2_kernel(
    const int* __restrict__ bsum, int* __restrict__ offsets,
    int* __restrict__ counts) {
  __shared__ int sb[SCAN_NB];
  int t = threadIdx.x, b = blockIdx.x;
  if (t < SCAN_NB) sb[t] = bsum[t];
  __syncthreads();
  int bpre = 0;
#pragma unroll
  for (int i = 0; i < SCAN_NB; ++i) {
    int tt = sb[i];
    if (i < b) bpre += tt;
  }
  int idx = b * 1024 + t;
  if (idx < N_NODES) {
    int v = offsets[idx] + bpre;
    offsets[idx] = v;
    counts[idx] = v;          // cursor for scatter
  }
  if (b == 0 && t == 0) offsets[N_NODES] = N_EDGES;
}

// =================== combo2: node_en (MFMA) | scatter ========================
// blocks [0,391)        : node_en via split-bf16 MFMA (wave = 16 nodes)
// blocks [391,391+1563) : scatter (CSR build), 512-thr
#define C2_EN 391
#define C2_SC 1563

__global__ void __launch_bounds__(512) combo2_kernel(
    const float* __restrict__ en, const ushort* __restrict__ wp,
    const float* __restrict__ pb0, const float* __restrict__ pb1,
    const float* __restrict__ pb2, const float* __restrict__ pb3,
    float* __restrict__ u, float* __restrict__ gp,
    const int* __restrict__ src, const int* __restrict__ dst,
    int* __restrict__ cursor, int2* __restrict__ csr) {
  const int b = blockIdx.x;
  const int tid = threadIdx.x;
  if (b < C2_EN) {
    // ----------------- node_en via MFMA -----------------
    __shared__ __align__(16) ushort lds[36864];   // 72 KB (node frag block)
    {
      const uint4* s4 = (const uint4*)(wp + 24576);
      uint4* d4 = (uint4*)lds;
      for (int i = tid; i < 4608; i += 512) d4[i] = s4[i];
    }
    __syncthreads();
    const int lane = tid & 63, q = lane >> 4, c = lane & 15, wv = tid >> 6;
    const int n = (b * 8 + wv) * 16 + c;
    const bool valid = n < N_NODES;

    float env[8];
#pragma unroll
    for (int j = 0; j < 8; ++j) env[j] = 0.f;
    if (valid) {
      const float4* p = (const float4*)(en + (long)n * 32 + q * 8);
      float4 e0 = p[0], e1 = p[1];
      env[0] = e0.x; env[1] = e0.y; env[2] = e0.z; env[3] = e0.w;
      env[4] = e1.x; env[5] = e1.y; env[6] = e1.z; env[7] = e1.w;
    }
    short8v beh, bel;
    split8(env, beh, bel);

    const short8v* TW0H = (const short8v*)(lds);
    const short8v* TW0L = (const short8v*)(lds + 2048);
    const short8v* PW0H = (const short8v*)(lds + 4096);
    const short8v* PW0L = (const short8v*)(lds + 6144);
    const short8v* NW1H = (const short8v*)(lds + 8192);
    const short8v* NW1L = (const short8v*)(lds + 16384);
    const short8v* NW2H = (const short8v*)(lds + 24576);
    const short8v* NW2L = (const short8v*)(lds + 28672);
    const short8v* NW3H = (const short8v*)(lds + 32768);
    const short8v* NW3L = (const short8v*)(lds + 34816);

    // u = en @ tW0 (4 tiles, natural K)
#pragma unroll
    for (int t = 0; t < 4; ++t) {
      f32x4 a = {0.f, 0.f, 0.f, 0.f};
      short8v ah = TW0H[t * 64 + lane], al = TW0L[t * 64 + lane];
      a = __builtin_amdgcn_mfma_f32_16x16x32_bf16(ah, beh, a, 0, 0, 0);
      a = __builtin_amdgcn_mfma_f32_16x16x32_bf16(al, beh, a, 0, 0, 0);
      a = __builtin_amdgcn_mfma_f32_16x16x32_bf16(ah, bel, a, 0, 0, 0);
      if (valid) *(f32x4*)(u + (long)n * 64 + t * 16 + q * 4) = a;
    }

    // h0 = relu(pW0^T en + b0)
    float h0v[4][4];
#pragma unroll
    for (int t = 0; t < 4; ++t) {
      f32x4 a = *(const f32x4*)(pb0 + t * 16 + q * 4);
      short8v ah = PW0H[t * 64 + lane], al = PW0L[t * 64 + lane];
      a = __builtin_amdgcn_mfma_f32_16x16x32_bf16(ah, beh, a, 0, 0, 0);
      a = __builtin_amdgcn_mfma_f32_16x16x32_bf16(al, beh, a, 0, 0, 0);
      a = __builtin_amdgcn_mfma_f32_16x16x32_bf16(ah, bel, a, 0, 0, 0);
#pragma unroll
      for (int g = 0; g < 4; ++g) h0v[t][g] = fmaxf(a[g], 0.f);
    }

    // L1 B frags via sigma1 (lane-local)
    short8v b1h[2], b1l[2];
#pragma unroll
    for (int f = 0; f < 2; ++f) {
      float tmp[8];
#pragma unroll
      for (int j = 0; j < 8; ++j) tmp[j] = h0v[2 * f + (j >> 2)][j & 3];
      split8(tmp, b1h[f], b1l[f]);
    }

    // L1: h1 = relu(pW1^T h0 + b1), 8 row-tiles x 2 k-frags
    float h1v[8][4];
#pragma unroll
    for (int r = 0; r < 8; ++r) {
      f32x4 a = *(const f32x4*)(pb1 + r * 16 + q * 4);
#pragma unroll
      for (int f = 0; f < 2; ++f) {
        short8v ah = NW1H[(r * 2 + f) * 64 + lane];
        short8v al = NW1L[(r * 2 + f) * 64 + lane];
        a = __builtin_amdgcn_mfma_f32_16x16x32_bf16(ah, b1h[f], a, 0, 0, 0);
        a = __builtin_amdgcn_mfma_f32_16x16x32_bf16(al, b1h[f], a, 0, 0, 0);
        a = __builtin_amdgcn_mfma_f32_16x16x32_bf16(ah, b1l[f], a, 0, 0, 0);
      }
#pragma unroll
      for (int g = 0; g < 4; ++g) h1v[r][g] = fmaxf(a[g], 0.f);
    }

    // L2 B frags via sigma (same as edge)
    short8v b2h[4], b2l[4];
#pragma unroll
    for (int f2 = 0; f2 < 4; ++f2) {
      float tmp[8];
#pragma unroll
      for (int j = 0; j < 8; ++j) tmp[j] = h1v[2 * f2 + (j >> 2)][j & 3];
      split8(tmp, b2h[f2], b2l[f2]);
    }

    // L2: h2 = relu(pW2^T h1 + b2), 2 tiles x 4 k-frags
    float h2v[2][4];
#pragma unroll
    for (int tt = 0; tt < 2; ++tt) {
      f32x4 a = *(const f32x4*)(pb2 + tt * 16 + q * 4);
#pragma unroll
      for (int f2 = 0; f2 < 4; ++f2) {
        short8v ah = NW2H[(tt * 4 + f2) * 64 + lane];
        short8v al = NW2L[(tt * 4 + f2) * 64 + lane];
        a = __builtin_amdgcn_mfma_f32_16x16x32_bf16(ah, b2h[f2], a, 0, 0, 0);
        a = __builtin_amdgcn_mfma_f32_16x16x32_bf16(al, b2h[f2], a, 0, 0, 0);
        a = __builtin_amdgcn_mfma_f32_16x16x32_bf16(ah, b2l[f2], a, 0, 0, 0);
      }
#pragma unroll
      for (int g = 0; g < 4; ++g) h2v[tt][g] = fmaxf(a[g], 0.f);
    }

    // L3 B frag via sigma3 (lane-local)
    short8v b3h, b3l;
    {
      float tmp[8];
#pragma unroll
      for (int j = 0; j < 8; ++j) tmp[j] = h2v[j >> 2][j & 3];
      split8(tmp, b3h, b3l);
    }

    // L3: pen = pW3^T h2 + b3 (4 tiles) -> gp[n][64:128]
#pragma unroll
    for (int t = 0; t < 4; ++t) {
      f32x4 a = *(const f32x4*)(pb3 + t * 16 + q * 4);
      short8v ah = NW3H[t * 64 + lane], al = NW3L[t * 64 + lane];
      a = __builtin_amdgcn_mfma_f32_16x16x32_bf16(ah, b3h, a, 0, 0, 0);
      a = __builtin_amdgcn_mfma_f32_16x16x32_bf16(al, b3h, a, 0, 0, 0);
      a = __builtin_amdgcn_mfma_f32_16x16x32_bf16(ah, b3l, a, 0, 0, 0);
      if (valid) *(f32x4*)(gp + (long)n * 128 + 64 + t * 16 + q * 4) = a;
    }
  } else {
    // ------------------------------ scatter --------------------------------
    int e = (b - C2_EN) * 512 + tid;
    if (e >= N_EDGES) return;
    int d = dst[e];
    int slot = atomicAdd(&cursor[d], 1);
    csr[slot] = make_int2(src[e], d);
  }
}

// ----------- per-edge theta MLP (layers 1,2) via split-bf16 MFMA -------------
__global__ void __launch_bounds__(512) mlp_edge_kernel(
    const float* __restrict__ u,
    const int2* __restrict__ csr,
    const float* __restrict__ b0g, const float* __restrict__ b1g,
    const float* __restrict__ b2g,
    const ushort* __restrict__ wp,
    float* __restrict__ h2sum) {
  __shared__ __align__(16) ushort lds[24576];   // 48 KB
  {
    const uint4* s4 = (const uint4*)wp;
    uint4* d4 = (uint4*)lds;
    for (int i = threadIdx.x; i < 3072; i += 512) d4[i] = s4[i];
  }
  __syncthreads();

  // bijective XCD swizzle (nwg=6250, q=781, r=2; m204 form)
  const int orig = blockIdx.x;
  const int xcd = orig & 7, loc = orig >> 3;
  const int blk = (xcd < 2) ? xcd * 782 + loc
                            : 2 * 782 + (xcd - 2) * 781 + loc;

  const int lane = threadIdx.x & 63;
  const int q = lane >> 4, c = lane & 15;
  const int wv = threadIdx.x >> 6;
  const int e = (blk * 8 + wv) * 16 + c;   // exact fit: 6250*128=800000
  const int2 pr = csr[e];
  const int s = pr.x, d = pr.y;

  const short8v* W1HI = (const short8v*)(lds);
  const short8v* W1LO = (const short8v*)(lds + 8192);
  const short8v* W2HI = (const short8v*)(lds + 16384);
  const short8v* W2LO = (const short8v*)(lds + 20480);

  short8v bh0, bl0, bh1, bl1;
  {
    const float* ud = u + (long)d * 64 + q * 8;
    const float* us = u + (long)s * 64 + q * 8;
    const float* bp = b0g + q * 8;
#pragma unroll
    for (int f = 0; f < 2; ++f) {
      float4 d0 = *(const float4*)(ud + f * 32);
      float4 d1 = *(const float4*)(ud + f * 32 + 4);
      float4 s0 = *(const float4*)(us + f * 32);
      float4 s1 = *(const float4*)(us + f * 32 + 4);
      float4 c0 = *(const float4*)(bp + f * 32);
      float4 c1 = *(const float4*)(bp + f * 32 + 4);
      float v[8];
      v[0] = fmaxf(d0.x - s0.x + c0.x, 0.f);
      v[1] = fmaxf(d0.y - s0.y + c0.y, 0.f);
      v[2] = fmaxf(d0.z - s0.z + c0.z, 0.f);
      v[3] = fmaxf(d0.w - s0.w + c0.w, 0.f);
      v[4] = fmaxf(d1.x - s1.x + c1.x, 0.f);
      v[5] = fmaxf(d1.y - s1.y + c1.y, 0.f);
      v[6] = fmaxf(d1.z - s1.z + c1.z, 0.f);
      v[7] = fmaxf(d1.w - s1.w + c1.w, 0.f);
      short8v hh, ll;
      split8(v, hh, ll);
      if (f == 0) { bh0 = hh; bl0 = ll; } else { bh1 = hh; bl1 = ll; }
    }
  }

  f32x4 acc[8];
#pragma unroll
  for (int r = 0; r < 8; ++r)
    acc[r] = *(const f32x4*)(b1g + r * 16 + q * 4);
#pragma unroll
  for (int r = 0; r < 8; ++r) {
    short8v ah0 = W1HI[(2 * r) * 64 + lane];
    short8v ah1 = W1HI[(2 * r + 1) * 64 + lane];
    short8v al0 = W1LO[(2 * r) * 64 + lane];
    short8v al1 = W1LO[(2 * r + 1) * 64 + lane];
    acc[r] = __builtin_amdgcn_mfma_f32_16x16x32_bf16(ah0, bh0, acc[r], 0, 0, 0);
    acc[r] = __builtin_amdgcn_mfma_f32_16x16x32_bf16(ah1, bh1, acc[r], 0, 0, 0);
    acc[r] = __builtin_amdgcn_mfma_f32_16x16x32_bf16(al0, bh0, acc[r], 0, 0, 0);
    acc[r] = __builtin_amdgcn_mfma_f32_16x16x32_bf16(al1, bh1, acc[r], 0, 0, 0);
    acc[r] = __builtin_amdgcn_mfma_f32_16x16x32_bf16(ah0, bl0, acc[r], 0, 0, 0);
    acc[r] = __builtin_amdgcn_mfma_f32_16x16x32_bf16(ah1, bl1, acc[r], 0, 0, 0);
  }
  float h1v[8][4];
#pragma unroll
  for (int r = 0; r < 8; ++r)
#pragma unroll
    for (int g = 0; g < 4; ++g) h1v[r][g] = fmaxf(acc[r][g], 0.f);

  short8v b2h[4], b2l[4];
#pragma unroll
  for (int f2 = 0; f2 < 4; ++f2) {
    float tmp[8];
#pragma unroll
    for (int j = 0; j < 8; ++j) tmp[j] = h1v[2 * f2 + (j >> 2)][j & 3];
    split8(tmp, b2h[f2], b2l[f2]);
  }

  f32x4 a20 = *(const f32x4*)(b2g + q * 4);
  f32x4 a21 = *(const f32x4*)(b2g + 16 + q * 4);
#pragma unroll
  for (int f2 = 0; f2 < 4; ++f2) {
    short8v ah = W2HI[f2 * 64 + lane];
    short8v al = W2LO[f2 * 64 + lane];
    a20 = __builtin_amdgcn_mfma_f32_16x16x32_bf16(ah, b2h[f2], a20, 0, 0, 0);
    a20 = __builtin_amdgcn_mfma_f32_16x16x32_bf16(al, b2h[f2], a20, 0, 0, 0);
    a20 = __builtin_amdgcn_mfma_f32_16x16x32_bf16(ah, b2l[f2], a20, 0, 0, 0);
    short8v ah1 = W2HI[(4 + f2) * 64 + lane];
    short8v al1 = W2LO[(4 + f2) * 64 + lane];
    a21 = __builtin_amdgcn_mfma_f32_16x16x32_bf16(ah1, b2h[f2], a21, 0, 0, 0);
    a21 = __builtin_amdgcn_mfma_f32_16x16x32_bf16(al1, b2h[f2], a21, 0, 0, 0);
    a21 = __builtin_amdgcn_mfma_f32_16x16x32_bf16(ah1, b2l[f2], a21, 0, 0, 0);
  }
  float h2v[8];
#pragma unroll
  for (int g = 0; g < 4; ++g) {
    h2v[g] = fmaxf(a20[g], 0.f);
    h2v[4 + g] = fmaxf(a21[g], 0.f);
  }

  // ---- 16-wide segmented inclusive sum along edge columns ----
  int dp = __shfl_up(d, 1, 16);
  bool head = (c == 0) || (dp != d);
  int seg = head ? c : 0;
#pragma unroll
  for (int off = 1; off < 16; off <<= 1) {
    int t = __shfl_up(seg, off, 16);
    if (c >= off) seg = max(seg, t);
  }
#pragma unroll
  for (int off = 1; off < 16; off <<= 1) {
    bool take = (c - off) >= seg;
#pragma unroll
    for (int k = 0; k < 8; ++k) {
      float t = __shfl_up(h2v[k], off, 16);
      if (take) h2v[k] += t;
    }
  }
  int dn = __shfl_down(d, 1, 16);
  bool tail = (c == 15) || (dn != d);
  if (tail) {
    float* hs = h2sum + (long)d * 32 + q * 4;
#pragma unroll
    for (int g = 0; g < 4; ++g) atomicAdd(&hs[g], h2v[g]);
#pragma unroll
    for (int g = 0; g < 4; ++g) atomicAdd(&hs[16 + g], h2v[4 + g]);
  }
}

// ------------------------- final gather / reduce -----------------------------
__global__ void __launch_bounds__(256) gather_kernel(
    const int2* __restrict__ csr, const int* __restrict__ offsets,
    const float* __restrict__ gp, const float* __restrict__ h2sum,
    const float* __restrict__ tW3, const float* __restrict__ tb3,
    float* __restrict__ out) {
  __shared__ float sW3[2048 + 64];
  for (int t = threadIdx.x; t < 2048; t += 256) sW3[t] = tW3[t];
  for (int t = threadIdx.x; t < 64; t += 256) sW3[2048 + t] = tb3[t];
  __syncthreads();
  int n = blockIdx.x * 8 + (threadIdx.x >> 5);
  int l = threadIdx.x & 31;
  int half = l >> 4, j4 = l & 15;
  int off = half * 64 + j4 * 4;
  int o0 = offsets[n], o1 = offsets[n + 1];
  int deg = o1 - o0;

  const float NEG = -3.402823466e38f;
  float4 mx = make_float4(NEG, NEG, NEG, NEG);
  float4 sm4 = make_float4(0.f, 0.f, 0.f, 0.f);
  for (int t = o0; t < o1; ++t) {
    int s = csr[t].x;
    float4 v = *(const float4*)(gp + (long)s * 128 + off);
    mx.x = fmaxf(mx.x, v.x); mx.y = fmaxf(mx.y, v.y);
    mx.z = fmaxf(mx.z, v.z); mx.w = fmaxf(mx.w, v.w);
    sm4.x += v.x; sm4.y += v.y; sm4.z += v.z; sm4.w += v.w;
  }

  float4 r;
  if (half == 0) {
    float4 a = *(const float4*)(out + (long)n * 128 + off);
    bool has = deg > 0;
    r.x = has ? a.x + mx.x : 0.f;
    r.y = has ? a.y + mx.y : 0.f;
    r.z = has ? a.z + mx.z : 0.f;
    r.w = has ? a.w + mx.w : 0.f;
  } else {
    int jj = j4 * 4;
    float w30 = 0.f, w31 = 0.f, w32 = 0.f, w33 = 0.f;
    const float* h2r = h2sum + (long)n * 32;
#pragma unroll
    for (int k = 0; k < 32; ++k) {
      float h = h2r[k];
      const float* wrow = &sW3[k * 64 + jj];
      w30 += h * wrow[0]; w31 += h * wrow[1];
      w32 += h * wrow[2]; w33 += h * wrow[3];
    }
    float dg = (float)deg;
    float inv = 1.f / fmaxf(dg, 1.f);
    r.x = (sm4.x + w30 + dg * sW3[2048 + jj + 0]) * inv;
    r.y = (sm4.y + w31 + dg * sW3[2048 + jj + 1]) * inv;
    r.z = (sm4.z + w32 + dg * sW3[2048 + jj + 2]) * inv;
    r.w = (sm4.w + w33 + dg * sW3[2048 + jj + 3]) * inv;
  }
  *(float4*)(out + (long)n * 128 + off) = r;
}

// ---------------------------------- launch -----------------------------------
extern "C" void kernel_launch(void* const* d_in, const int* in_sizes, int n_in,
                              void* d_out, int out_size, void* d_ws,
                              size_t ws_size, hipStream_t stream) {
  const float* x   = (const float*)d_in[0];
  const float* en  = (const float*)d_in[1];
  const int* src   = (const int*)d_in[2];
  const int* dst   = (const int*)d_in[3];
  const float* thW = (const float*)d_in[4];
  const float* thB = (const float*)d_in[5];
  const float* phW = (const float*)d_in[6];
  const float* phB = (const float*)d_in[7];
  const float* tW0 = (const float*)d_in[8];
  const float* tb0 = (const float*)d_in[9];
  const float* tW1 = (const float*)d_in[10];
  const float* tb1 = (const float*)d_in[11];
  const float* tW2 = (const float*)d_in[12];
  const float* tb2 = (const float*)d_in[13];
  const float* tW3 = (const float*)d_in[14];
  const float* tb3 = (const float*)d_in[15];
  const float* pW0 = (const float*)d_in[16];
  const float* pb0 = (const float*)d_in[17];
  const float* pW1 = (const float*)d_in[18];
  const float* pb1 = (const float*)d_in[19];
  const float* pW2 = (const float*)d_in[20];
  const float* pb2 = (const float*)d_in[21];
  const float* pW3 = (const float*)d_in[22];
  const float* pb3 = (const float*)d_in[23];

  float* out = (float*)d_out;
  float* ws  = (float*)d_ws;
  // ws layout (floats): gp[N*128], u[N*64], h2sum[N*32], wpack[30720], ints
  float* gp     = ws;                           // 6,400,000
  float* u      = ws + (long)N_NODES * 128;     // 3,200,000
  float* h2sum  = ws + (long)N_NODES * 192;     // 1,600,000
  float* wpf    = ws + (long)N_NODES * 224;     // 30,720 floats (61440 ushorts)
  ushort* wp    = (ushort*)wpf;
  int* iw       = (int*)(wpf + 30720);
  int2* csr     = (int2*)iw;                    // E pairs (src,dst)
  int* counts   = iw + 2 * N_EDGES;             // N (becomes cursor)
  int* offsets  = counts + N_NODES;             // N+1
  int* bsum     = offsets + N_NODES + 1;        // SCAN_NB
  // total ws ≈ 51.8 MB

  hipMemsetAsync(counts, 0, N_NODES * sizeof(int), stream);
  hipMemsetAsync(h2sum, 0, (size_t)N_NODES * 32 * sizeof(float), stream);
  combo1_kernel<<<C1_X + C1_CNT + C1_PACK, 256, 0, stream>>>(
      x, thW, thB, phW, phB, out, gp, dst, counts,
      tW1, tW2, tW0, pW0, pW1, pW2, pW3, wp);
  scan1_kernel<<<SCAN_NB, 1024, 0, stream>>>(counts, offsets, bsum);
  scan2_kernel<<<SCAN_NB, 1024, 0, stream>>>(bsum, offsets, counts);
  combo2_kernel<<<C2_EN + C2_SC, 512, 0, stream>>>(
      en, wp, pb0, pb1, pb2, pb3, u, gp, src, dst, counts, csr);
  mlp_edge_kernel<<<N_EDGES / 128, 512, 0, stream>>>(
      u, csr, tb0, tb1, tb2, wp, h2sum);
  gather_kernel<<<N_NODES / 8, 256, 0, stream>>>(
      csr, offsets, gp, h2sum, tW3, tb3, out);
}